// Round 1
// baseline (3179.363 us; speedup 1.0000x reference)
//
#include <hip/hip_runtime.h>
#include <hip/hip_bf16.h>
#include <math.h>

#define N_NODES 50000
#define N_EDGES 1600000
#define CH 128
#define NF 50

constexpr float DELTA = 5.0f / 49.0f;              // linspace(0,5,50) spacing
constexpr float COEF  = 1.0f / (2.0f * DELTA * DELTA);
constexpr float LOG2_ = 0.6931471805599453f;

__device__ __forceinline__ float ssp(float x) {
    // softplus(x) - log(2), numerically stable
    return fmaxf(x, 0.0f) + log1pf(__expf(-fabsf(x))) - LOG2_;
}

__device__ __forceinline__ float4 f4zero() { return make_float4(0.f, 0.f, 0.f, 0.f); }

__device__ __forceinline__ void f4fma(float4& acc, float a, const float4& w) {
    acc.x = fmaf(a, w.x, acc.x);
    acc.y = fmaf(a, w.y, acc.y);
    acc.z = fmaf(a, w.z, acc.z);
    acc.w = fmaf(a, w.w, acc.w);
}

__device__ __forceinline__ float dot4(const float4& a, const float4& b) {
    return fmaf(a.x, b.x, fmaf(a.y, b.y, fmaf(a.z, b.z, a.w * b.w)));
}

// ---------------------------------------------------------------------------
// Generic Y = act(X @ W(^T) + b) for [M,128] x [128,128].
// Block: 256 threads, 16 rows. Thread: 2 rows x 4 channels.
// ---------------------------------------------------------------------------
template <bool TRANSB, bool BIAS, bool ACT>
__global__ __launch_bounds__(256) void dense128(const float* __restrict__ X,
                                                const float* __restrict__ W,
                                                const float* __restrict__ b,
                                                float* __restrict__ Y) {
    __shared__ float Xs[16][132];   // pad 132: keeps float4 alignment (528B rows)
    const int tid  = threadIdx.x;
    const int row0 = blockIdx.x * 16;

    for (int i = tid; i < 16 * 128; i += 256) {
        int r = i >> 7, k = i & 127;
        Xs[r][k] = X[(size_t)(row0 + r) * CH + k];
    }
    __syncthreads();

    const int cq = tid & 31;   // channel quad: channels cq*4 .. cq*4+3
    const int rg = tid >> 5;   // rows rg*2, rg*2+1
    const int c4 = cq * 4;

    float4 acc0 = f4zero(), acc1 = f4zero();

    for (int k = 0; k < 128; k += 4) {
        float4 x0 = *(const float4*)&Xs[rg * 2 + 0][k];
        float4 x1 = *(const float4*)&Xs[rg * 2 + 1][k];
        if (TRANSB) {
            // y[c] = sum_k x[k] * W[c][k]
            float4 w0 = *(const float4*)&W[(size_t)(c4 + 0) * CH + k];
            float4 w1 = *(const float4*)&W[(size_t)(c4 + 1) * CH + k];
            float4 w2 = *(const float4*)&W[(size_t)(c4 + 2) * CH + k];
            float4 w3 = *(const float4*)&W[(size_t)(c4 + 3) * CH + k];
            acc0.x += dot4(x0, w0); acc0.y += dot4(x0, w1);
            acc0.z += dot4(x0, w2); acc0.w += dot4(x0, w3);
            acc1.x += dot4(x1, w0); acc1.y += dot4(x1, w1);
            acc1.z += dot4(x1, w2); acc1.w += dot4(x1, w3);
        } else {
            // y[c] = sum_k x[k] * W[k][c]
            float4 w0 = *(const float4*)&W[(size_t)(k + 0) * CH + c4];
            float4 w1 = *(const float4*)&W[(size_t)(k + 1) * CH + c4];
            float4 w2 = *(const float4*)&W[(size_t)(k + 2) * CH + c4];
            float4 w3 = *(const float4*)&W[(size_t)(k + 3) * CH + c4];
            f4fma(acc0, x0.x, w0); f4fma(acc0, x0.y, w1);
            f4fma(acc0, x0.z, w2); f4fma(acc0, x0.w, w3);
            f4fma(acc1, x1.x, w0); f4fma(acc1, x1.y, w1);
            f4fma(acc1, x1.z, w2); f4fma(acc1, x1.w, w3);
        }
    }

    if (BIAS) {
        float4 bb = *(const float4*)&b[c4];
        acc0.x += bb.x; acc0.y += bb.y; acc0.z += bb.z; acc0.w += bb.w;
        acc1.x += bb.x; acc1.y += bb.y; acc1.z += bb.z; acc1.w += bb.w;
    }
    if (ACT) {
        acc0.x = ssp(acc0.x); acc0.y = ssp(acc0.y); acc0.z = ssp(acc0.z); acc0.w = ssp(acc0.w);
        acc1.x = ssp(acc1.x); acc1.y = ssp(acc1.y); acc1.z = ssp(acc1.z); acc1.w = ssp(acc1.w);
    }
    *(float4*)&Y[(size_t)(row0 + rg * 2 + 0) * CH + c4] = acc0;
    *(float4*)&Y[(size_t)(row0 + rg * 2 + 1) * CH + c4] = acc1;
}

// ---------------------------------------------------------------------------
// Fused edge kernel: basis -> filter MLP -> gather h[sender] -> * ->
// atomic scatter-add to agg[receiver]. Block: 256 threads, 64 edges.
// Thread: 8 edges (eg group) x 4 channels (cq quad).
// ---------------------------------------------------------------------------
__global__ __launch_bounds__(256) void edge_kernel(const float* __restrict__ dist,
                                                   const float* __restrict__ Wf1,
                                                   const float* __restrict__ bf1,
                                                   const float* __restrict__ Wf2,
                                                   const float* __restrict__ bf2,
                                                   const float* __restrict__ h,
                                                   const int* __restrict__ senders,
                                                   const int* __restrict__ receivers,
                                                   float* __restrict__ agg) {
    __shared__ float bas[64][52];    // 52-float rows: 208B, 16B-aligned
    __shared__ float t1s[64][132];   // 528B rows, 16B-aligned

    const int tid = threadIdx.x;
    const int e0  = blockIdx.x * 64;

    // Phase 0: Gaussian smearing basis for 64 edges.
    for (int i = tid; i < 64 * NF; i += 256) {
        int e = i / NF;
        int f = i - e * NF;
        float r = dist[e0 + e];
        float d = r - (float)f * DELTA;
        bas[e][f] = __expf(-COEF * d * d);
    }
    __syncthreads();

    const int cq = tid & 31;
    const int eg = tid >> 5;   // edges eg*8 .. eg*8+7
    const int c4 = cq * 4;

    float4 acc[8];
#pragma unroll
    for (int i = 0; i < 8; i++) acc[i] = f4zero();

    // Phase 1: t1 = ssp(bas @ Wf1 + bf1), K = 50 (48 vectorized + 2 tail)
    for (int k = 0; k < 48; k += 4) {
        float4 w0 = *(const float4*)&Wf1[(size_t)(k + 0) * CH + c4];
        float4 w1 = *(const float4*)&Wf1[(size_t)(k + 1) * CH + c4];
        float4 w2 = *(const float4*)&Wf1[(size_t)(k + 2) * CH + c4];
        float4 w3 = *(const float4*)&Wf1[(size_t)(k + 3) * CH + c4];
#pragma unroll
        for (int i = 0; i < 8; i++) {
            float4 bb = *(const float4*)&bas[eg * 8 + i][k];
            f4fma(acc[i], bb.x, w0); f4fma(acc[i], bb.y, w1);
            f4fma(acc[i], bb.z, w2); f4fma(acc[i], bb.w, w3);
        }
    }
    {
        float4 w0 = *(const float4*)&Wf1[(size_t)48 * CH + c4];
        float4 w1 = *(const float4*)&Wf1[(size_t)49 * CH + c4];
#pragma unroll
        for (int i = 0; i < 8; i++) {
            float b0 = bas[eg * 8 + i][48];
            float b1 = bas[eg * 8 + i][49];
            f4fma(acc[i], b0, w0); f4fma(acc[i], b1, w1);
        }
    }
    {
        float4 bb1 = *(const float4*)&bf1[c4];
#pragma unroll
        for (int i = 0; i < 8; i++) {
            float4 v = acc[i];
            v.x = ssp(v.x + bb1.x); v.y = ssp(v.y + bb1.y);
            v.z = ssp(v.z + bb1.z); v.w = ssp(v.w + bb1.w);
            *(float4*)&t1s[eg * 8 + i][c4] = v;
        }
    }
    __syncthreads();

    // Phase 2: ef = t1 @ Wf2 + bf2, K = 128
#pragma unroll
    for (int i = 0; i < 8; i++) acc[i] = f4zero();

    for (int k = 0; k < 128; k += 4) {
        float4 w0 = *(const float4*)&Wf2[(size_t)(k + 0) * CH + c4];
        float4 w1 = *(const float4*)&Wf2[(size_t)(k + 1) * CH + c4];
        float4 w2 = *(const float4*)&Wf2[(size_t)(k + 2) * CH + c4];
        float4 w3 = *(const float4*)&Wf2[(size_t)(k + 3) * CH + c4];
#pragma unroll
        for (int i = 0; i < 8; i++) {
            float4 t = *(const float4*)&t1s[eg * 8 + i][k];
            f4fma(acc[i], t.x, w0); f4fma(acc[i], t.y, w1);
            f4fma(acc[i], t.z, w2); f4fma(acc[i], t.w, w3);
        }
    }

    // Epilogue: messages + scatter
    float4 bb2 = *(const float4*)&bf2[c4];
#pragma unroll
    for (int i = 0; i < 8; i++) {
        int e = e0 + eg * 8 + i;
        int s = senders[e];
        int r = receivers[e];
        float4 hv = *(const float4*)&h[(size_t)s * CH + c4];
        float4 ef = acc[i];
        ef.x += bb2.x; ef.y += bb2.y; ef.z += bb2.z; ef.w += bb2.w;
        float* dst = &agg[(size_t)r * CH + c4];
        unsafeAtomicAdd(dst + 0, hv.x * ef.x);
        unsafeAtomicAdd(dst + 1, hv.y * ef.y);
        unsafeAtomicAdd(dst + 2, hv.z * ef.z);
        unsafeAtomicAdd(dst + 3, hv.w * ef.w);
    }
}

// ---------------------------------------------------------------------------
extern "C" void kernel_launch(void* const* d_in, const int* in_sizes, int n_in,
                              void* d_out, int out_size, void* d_ws, size_t ws_size,
                              hipStream_t stream) {
    const float* features = (const float*)d_in[0];
    const float* dist     = (const float*)d_in[1];
    const float* W_lin    = (const float*)d_in[2];
    const float* Wf1      = (const float*)d_in[3];
    const float* bf1      = (const float*)d_in[4];
    const float* Wf2      = (const float*)d_in[5];
    const float* bf2      = (const float*)d_in[6];
    const float* Wm1      = (const float*)d_in[7];
    const float* bm1      = (const float*)d_in[8];
    const float* Wm2      = (const float*)d_in[9];
    const float* bm2      = (const float*)d_in[10];
    const int* senders    = (const int*)d_in[11];
    const int* receivers  = (const int*)d_in[12];
    float* out = (float*)d_out;

    float* h   = (float*)d_ws;                      // [N, 128], later reused as t
    float* agg = h + (size_t)N_NODES * CH;          // [N, 128]

    hipMemsetAsync(agg, 0, (size_t)N_NODES * CH * sizeof(float), stream);

    // h = features @ W_lin^T
    dense128<true, false, false><<<N_NODES / 16, 256, 0, stream>>>(features, W_lin, nullptr, h);

    // fused edge pipeline -> agg
    edge_kernel<<<N_EDGES / 64, 256, 0, stream>>>(dist, Wf1, bf1, Wf2, bf2, h,
                                                  senders, receivers, agg);

    // t = ssp(agg @ Wm1 + bm1)   (t reuses h's buffer)
    dense128<false, true, true><<<N_NODES / 16, 256, 0, stream>>>(agg, Wm1, bm1, h);

    // out = t @ Wm2 + bm2
    dense128<false, true, false><<<N_NODES / 16, 256, 0, stream>>>(h, Wm2, bm2, out);
}

// Round 2
// 1677.388 us; speedup vs baseline: 1.8954x; 1.8954x over previous
//
#include <hip/hip_runtime.h>
#include <hip/hip_bf16.h>
#include <math.h>

#define N_NODES 50000
#define N_EDGES 1600000
#define CH 128
#define NF 50

constexpr float DELTA = 5.0f / 49.0f;              // linspace(0,5,50) spacing
constexpr float COEF  = 1.0f / (2.0f * DELTA * DELTA);
constexpr float LOG2_ = 0.6931471805599453f;

typedef short  bf16x8 __attribute__((ext_vector_type(8)));
typedef float  f32x4  __attribute__((ext_vector_type(4)));
typedef unsigned short ushort_t;

__device__ __forceinline__ float ssp(float x) {
    return fmaxf(x, 0.0f) + log1pf(__expf(-fabsf(x))) - LOG2_;
}

// round-to-nearest-even f32 -> bf16 bits (no NaN handling needed here)
__device__ __forceinline__ ushort_t f2bf(float x) {
    unsigned u = __float_as_uint(x);
    unsigned r = (u + 0x7fffu + ((u >> 16) & 1u)) >> 16;
    return (ushort_t)r;
}
__device__ __forceinline__ float bf2f(ushort_t u) {
    return __uint_as_float(((unsigned)u) << 16);
}

__device__ __forceinline__ float4 f4zero() { return make_float4(0.f, 0.f, 0.f, 0.f); }
__device__ __forceinline__ void f4fma(float4& acc, float a, const float4& w) {
    acc.x = fmaf(a, w.x, acc.x); acc.y = fmaf(a, w.y, acc.y);
    acc.z = fmaf(a, w.z, acc.z); acc.w = fmaf(a, w.w, acc.w);
}
__device__ __forceinline__ float dot4(const float4& a, const float4& b) {
    return fmaf(a.x, b.x, fmaf(a.y, b.y, fmaf(a.z, b.z, a.w * b.w)));
}

// ---------------------------------------------------------------------------
// Dense [M,128]x[128,128] (node-side GEMMs, fp32 VALU) — unchanged from R1.
// ---------------------------------------------------------------------------
template <bool TRANSB, bool BIAS, bool ACT>
__global__ __launch_bounds__(256) void dense128(const float* __restrict__ X,
                                                const float* __restrict__ W,
                                                const float* __restrict__ b,
                                                float* __restrict__ Y) {
    __shared__ float Xs[16][132];
    const int tid  = threadIdx.x;
    const int row0 = blockIdx.x * 16;

    for (int i = tid; i < 16 * 128; i += 256) {
        int r = i >> 7, k = i & 127;
        Xs[r][k] = X[(size_t)(row0 + r) * CH + k];
    }
    __syncthreads();

    const int cq = tid & 31;
    const int rg = tid >> 5;
    const int c4 = cq * 4;

    float4 acc0 = f4zero(), acc1 = f4zero();

    for (int k = 0; k < 128; k += 4) {
        float4 x0 = *(const float4*)&Xs[rg * 2 + 0][k];
        float4 x1 = *(const float4*)&Xs[rg * 2 + 1][k];
        if (TRANSB) {
            float4 w0 = *(const float4*)&W[(size_t)(c4 + 0) * CH + k];
            float4 w1 = *(const float4*)&W[(size_t)(c4 + 1) * CH + k];
            float4 w2 = *(const float4*)&W[(size_t)(c4 + 2) * CH + k];
            float4 w3 = *(const float4*)&W[(size_t)(c4 + 3) * CH + k];
            acc0.x += dot4(x0, w0); acc0.y += dot4(x0, w1);
            acc0.z += dot4(x0, w2); acc0.w += dot4(x0, w3);
            acc1.x += dot4(x1, w0); acc1.y += dot4(x1, w1);
            acc1.z += dot4(x1, w2); acc1.w += dot4(x1, w3);
        } else {
            float4 w0 = *(const float4*)&W[(size_t)(k + 0) * CH + c4];
            float4 w1 = *(const float4*)&W[(size_t)(k + 1) * CH + c4];
            float4 w2 = *(const float4*)&W[(size_t)(k + 2) * CH + c4];
            float4 w3 = *(const float4*)&W[(size_t)(k + 3) * CH + c4];
            f4fma(acc0, x0.x, w0); f4fma(acc0, x0.y, w1);
            f4fma(acc0, x0.z, w2); f4fma(acc0, x0.w, w3);
            f4fma(acc1, x1.x, w0); f4fma(acc1, x1.y, w1);
            f4fma(acc1, x1.z, w2); f4fma(acc1, x1.w, w3);
        }
    }

    if (BIAS) {
        float4 bb = *(const float4*)&b[c4];
        acc0.x += bb.x; acc0.y += bb.y; acc0.z += bb.z; acc0.w += bb.w;
        acc1.x += bb.x; acc1.y += bb.y; acc1.z += bb.z; acc1.w += bb.w;
    }
    if (ACT) {
        acc0.x = ssp(acc0.x); acc0.y = ssp(acc0.y); acc0.z = ssp(acc0.z); acc0.w = ssp(acc0.w);
        acc1.x = ssp(acc1.x); acc1.y = ssp(acc1.y); acc1.z = ssp(acc1.z); acc1.w = ssp(acc1.w);
    }
    *(float4*)&Y[(size_t)(row0 + rg * 2 + 0) * CH + c4] = acc0;
    *(float4*)&Y[(size_t)(row0 + rg * 2 + 1) * CH + c4] = acc1;
}

// ---------------------------------------------------------------------------
// Weight prep: bf16 transposed copies. Wf1T[c][k] (k padded 50->64),
// Wf2T hi/lo split [c][k] for 3-term bf16 GEMM (fp32-class accuracy).
// ---------------------------------------------------------------------------
__global__ __launch_bounds__(256) void prep_weights(const float* __restrict__ Wf1,
                                                    const float* __restrict__ Wf2,
                                                    ushort_t* __restrict__ wf1t,
                                                    ushort_t* __restrict__ wf2hi,
                                                    ushort_t* __restrict__ wf2lo) {
    int idx = blockIdx.x * 256 + threadIdx.x;   // 0..16383
    int c = idx >> 7, k = idx & 127;
    if (k < 64) wf1t[c * 64 + k] = (k < NF) ? f2bf(Wf1[k * CH + c]) : (ushort_t)0;
    float w = Wf2[(size_t)k * CH + c];
    ushort_t hi = f2bf(w);
    wf2hi[c * CH + k] = hi;
    wf2lo[c * CH + k] = f2bf(w - bf2f(hi));
}

// ---------------------------------------------------------------------------
// Counting sort of edges by receiver.
// ---------------------------------------------------------------------------
__global__ __launch_bounds__(256) void hist_kernel(const int* __restrict__ recv,
                                                   int* __restrict__ counts) {
    int e = blockIdx.x * 256 + threadIdx.x;
    if (e < N_EDGES) atomicAdd(&counts[recv[e]], 1);
}

__global__ __launch_bounds__(256) void scan1_kernel(const int* __restrict__ counts,
                                                    int* __restrict__ cursor,
                                                    int* __restrict__ bsum) {
    __shared__ int s[256];
    int tid = threadIdx.x;
    int i = blockIdx.x * 256 + tid;
    int v = (i < N_NODES) ? counts[i] : 0;
    s[tid] = v;
    __syncthreads();
    for (int off = 1; off < 256; off <<= 1) {
        int t = (tid >= off) ? s[tid - off] : 0;
        __syncthreads();
        s[tid] += t;
        __syncthreads();
    }
    if (i < N_NODES) cursor[i] = s[tid] - v;           // exclusive within block
    if (tid == 255) bsum[blockIdx.x] = s[255];
}

__global__ __launch_bounds__(256) void scan2_kernel(int* __restrict__ bsum, int nb) {
    __shared__ int s[256];
    int tid = threadIdx.x;
    int v = (tid < nb) ? bsum[tid] : 0;
    s[tid] = v;
    __syncthreads();
    for (int off = 1; off < 256; off <<= 1) {
        int t = (tid >= off) ? s[tid - off] : 0;
        __syncthreads();
        s[tid] += t;
        __syncthreads();
    }
    if (tid < nb) bsum[tid] = s[tid] - v;              // exclusive
}

__global__ __launch_bounds__(256) void scan3_kernel(int* __restrict__ cursor,
                                                    const int* __restrict__ bsum) {
    int i = blockIdx.x * 256 + threadIdx.x;
    if (i < N_NODES) cursor[i] += bsum[blockIdx.x];
}

__global__ __launch_bounds__(256) void scatter_kernel(const int* __restrict__ recv,
                                                      int* __restrict__ cursor,
                                                      int* __restrict__ perm) {
    int e = blockIdx.x * 256 + threadIdx.x;
    if (e < N_EDGES) {
        int pos = atomicAdd(&cursor[recv[e]], 1);
        perm[pos] = e;
    }
}

// ---------------------------------------------------------------------------
// Fused edge kernel over receiver-sorted edges.
// Block = 256 thr = 4 waves, 64 edges. Wave w owns edge-tile rows w*16..w*16+15.
// GEMM1: basis[64x64bf16] @ Wf1T  (16x16x32 MFMA, 2 k-steps)
// GEMM2: t1 @ Wf2, 3-term bf16 split (hi*hi + hi*lo + lo*hi)
// Aggregation: per-block 16-slot LDS accumulator (sorted => ~3 distinct
// receivers/block), one global atomic per (slot,channel) at flush.
// ---------------------------------------------------------------------------
__global__ __launch_bounds__(256) void edge_kernel(const float* __restrict__ dist,
                                                   const int* __restrict__ senders,
                                                   const int* __restrict__ receivers,
                                                   const int* __restrict__ perm,
                                                   const ushort_t* __restrict__ wf1t,
                                                   const float* __restrict__ bf1,
                                                   const ushort_t* __restrict__ wf2hi,
                                                   const ushort_t* __restrict__ wf2lo,
                                                   const float* __restrict__ bf2,
                                                   const float* __restrict__ h,
                                                   float* __restrict__ agg) {
    __shared__ ushort_t basis[64][72];   // 144B rows: bank stride 4 -> 2-way (free)
    __shared__ ushort_t t1hi[64][136];   // 272B rows: bank stride 4 -> 2-way
    __shared__ ushort_t t1lo[64][136];
    __shared__ float aggS[16][128];
    __shared__ float dist_s[64];
    __shared__ int r_s[64], sid_s[64], slot_s[64], slotr_s[16];
    __shared__ int nslots_s;

    const int tid = threadIdx.x;
    const int e0  = blockIdx.x * 64;

    if (tid < 64) {
        int eid = perm[e0 + tid];
        dist_s[tid] = dist[eid];
        r_s[tid]    = receivers[eid];
        sid_s[tid]  = senders[eid];
    }
    for (int i = tid; i < 16 * 128; i += 256) ((float*)aggS)[i] = 0.f;
    __syncthreads();

    // slot assignment (rank of distinct receiver within block), wave 0 only
    if (tid < 64) {
        int lane = tid;
        int flag = (lane > 0 && r_s[lane] != r_s[lane - 1]) ? 1 : 0;
        int v = flag;
        for (int off = 1; off < 64; off <<= 1) {
            int u = __shfl_up(v, off);
            if (lane >= off) v += u;
        }
        slot_s[lane] = v;
        if ((flag || lane == 0) && v < 16) slotr_s[v] = r_s[lane];
        if (lane == 63) nslots_s = v + 1;
    }
    // Gaussian basis -> bf16 LDS (k padded to 64 with zeros)
    for (int i = tid; i < 64 * 64; i += 256) {
        int e = i >> 6, k = i & 63;
        float val = 0.f;
        if (k < NF) {
            float d = dist_s[e] - (float)k * DELTA;
            val = __expf(-COEF * d * d);
        }
        basis[e][k] = f2bf(val);
    }
    __syncthreads();

    const int wv   = tid >> 6;
    const int lane = tid & 63;
    const int row  = lane & 15;
    const int quad = lane >> 4;

    f32x4 acc[8];
#pragma unroll
    for (int ct = 0; ct < 8; ct++) acc[ct] = (f32x4){0.f, 0.f, 0.f, 0.f};

    // ---- GEMM1: t1 = ssp(basis @ Wf1 + bf1) ----
#pragma unroll
    for (int kb = 0; kb < 64; kb += 32) {
        bf16x8 A = *(const bf16x8*)&basis[wv * 16 + row][kb + quad * 8];
#pragma unroll
        for (int ct = 0; ct < 8; ct++) {
            bf16x8 B = *(const bf16x8*)&wf1t[(ct * 16 + row) * 64 + kb + quad * 8];
            acc[ct] = __builtin_amdgcn_mfma_f32_16x16x32_bf16(A, B, acc[ct], 0, 0, 0);
        }
    }
#pragma unroll
    for (int ct = 0; ct < 8; ct++) {
        int c = ct * 16 + row;
        float b = bf1[c];
#pragma unroll
        for (int rg = 0; rg < 4; rg++) {
            int e = wv * 16 + quad * 4 + rg;
            float t = ssp(acc[ct][rg] + b);
            ushort_t hi = f2bf(t);
            t1hi[e][c] = hi;
            t1lo[e][c] = f2bf(t - bf2f(hi));
        }
    }
    __syncthreads();

    // ---- GEMM2: ef = t1 @ Wf2 + bf2 (3-term bf16 split) ----
#pragma unroll
    for (int ct = 0; ct < 8; ct++) acc[ct] = (f32x4){0.f, 0.f, 0.f, 0.f};

#pragma unroll
    for (int kb = 0; kb < 128; kb += 32) {
        bf16x8 Ah = *(const bf16x8*)&t1hi[wv * 16 + row][kb + quad * 8];
        bf16x8 Al = *(const bf16x8*)&t1lo[wv * 16 + row][kb + quad * 8];
#pragma unroll
        for (int ct = 0; ct < 8; ct++) {
            bf16x8 Bh = *(const bf16x8*)&wf2hi[(ct * 16 + row) * 128 + kb + quad * 8];
            bf16x8 Bl = *(const bf16x8*)&wf2lo[(ct * 16 + row) * 128 + kb + quad * 8];
            acc[ct] = __builtin_amdgcn_mfma_f32_16x16x32_bf16(Ah, Bh, acc[ct], 0, 0, 0);
            acc[ct] = __builtin_amdgcn_mfma_f32_16x16x32_bf16(Ah, Bl, acc[ct], 0, 0, 0);
            acc[ct] = __builtin_amdgcn_mfma_f32_16x16x32_bf16(Al, Bh, acc[ct], 0, 0, 0);
        }
    }

    // ---- epilogue: message = h[sender]*ef, accumulate into LDS slots ----
    const int eb = wv * 16 + quad * 4;
    int sid[4], slt[4], rcv[4];
#pragma unroll
    for (int rg = 0; rg < 4; rg++) {
        sid[rg] = sid_s[eb + rg];
        slt[rg] = slot_s[eb + rg];
        rcv[rg] = r_s[eb + rg];
    }
    const bool uni = (slt[0] == slt[3]);   // slots are monotone in rg

#pragma unroll
    for (int ct = 0; ct < 8; ct++) {
        int c = ct * 16 + row;
        float b2 = bf2[c];
        float m[4];
#pragma unroll
        for (int rg = 0; rg < 4; rg++)
            m[rg] = h[(size_t)sid[rg] * CH + c] * (acc[ct][rg] + b2);
        if (uni) {
            float sum = (m[0] + m[1]) + (m[2] + m[3]);
            if (slt[0] < 16) atomicAdd(&aggS[slt[0]][c], sum);
            else             unsafeAtomicAdd(&agg[(size_t)rcv[0] * CH + c], sum);
        } else {
#pragma unroll
            for (int rg = 0; rg < 4; rg++) {
                if (slt[rg] < 16) atomicAdd(&aggS[slt[rg]][c], m[rg]);
                else              unsafeAtomicAdd(&agg[(size_t)rcv[rg] * CH + c], m[rg]);
            }
        }
    }
    __syncthreads();

    // flush slots -> global (one atomic per slot-channel; receivers can span blocks)
    int ns = nslots_s < 16 ? nslots_s : 16;
    for (int i = tid; i < ns * 128; i += 256) {
        int s = i >> 7, c = i & 127;
        unsafeAtomicAdd(&agg[(size_t)slotr_s[s] * CH + c], aggS[s][c]);
    }
}

// ---------------------------------------------------------------------------
extern "C" void kernel_launch(void* const* d_in, const int* in_sizes, int n_in,
                              void* d_out, int out_size, void* d_ws, size_t ws_size,
                              hipStream_t stream) {
    const float* features = (const float*)d_in[0];
    const float* dist     = (const float*)d_in[1];
    const float* W_lin    = (const float*)d_in[2];
    const float* Wf1      = (const float*)d_in[3];
    const float* bf1      = (const float*)d_in[4];
    const float* Wf2      = (const float*)d_in[5];
    const float* bf2      = (const float*)d_in[6];
    const float* Wm1      = (const float*)d_in[7];
    const float* bm1      = (const float*)d_in[8];
    const float* Wm2      = (const float*)d_in[9];
    const float* bm2      = (const float*)d_in[10];
    const int* senders    = (const int*)d_in[11];
    const int* receivers  = (const int*)d_in[12];
    float* out = (float*)d_out;

    // workspace layout (~33 MB)
    float* h       = (float*)d_ws;                         // [N,128] f32, reused as t
    int*   perm    = (int*)(h + (size_t)N_NODES * CH);     // [E]
    int*   counts  = perm + N_EDGES;                       // [N]
    int*   cursor  = counts + N_NODES;                     // [N]
    int*   bsum    = cursor + N_NODES;                     // [256]
    ushort_t* wf1t  = (ushort_t*)(bsum + 256);             // [128*64]
    ushort_t* wf2hi = wf1t + 128 * 64;                     // [128*128]
    ushort_t* wf2lo = wf2hi + 128 * 128;                   // [128*128]

    float* agg = out;   // accumulate segment-sum directly in d_out

    hipMemsetAsync(counts, 0, (size_t)N_NODES * sizeof(int), stream);
    hipMemsetAsync(agg, 0, (size_t)N_NODES * CH * sizeof(float), stream);

    prep_weights<<<64, 256, 0, stream>>>(Wf1, Wf2, wf1t, wf2hi, wf2lo);

    // counting sort by receiver
    const int nb_scan = (N_NODES + 255) / 256;   // 196
    hist_kernel<<<(N_EDGES + 255) / 256, 256, 0, stream>>>(receivers, counts);
    scan1_kernel<<<nb_scan, 256, 0, stream>>>(counts, cursor, bsum);
    scan2_kernel<<<1, 256, 0, stream>>>(bsum, nb_scan);
    scan3_kernel<<<nb_scan, 256, 0, stream>>>(cursor, bsum);
    scatter_kernel<<<(N_EDGES + 255) / 256, 256, 0, stream>>>(receivers, cursor, perm);

    // h = features @ W_lin^T
    dense128<true, false, false><<<N_NODES / 16, 256, 0, stream>>>(features, W_lin, nullptr, h);

    // fused edge pipeline (sorted) -> agg (= d_out)
    edge_kernel<<<N_EDGES / 64, 256, 0, stream>>>(dist, senders, receivers, perm,
                                                  wf1t, bf1, wf2hi, wf2lo, bf2, h, agg);

    // t = ssp(agg @ Wm1 + bm1)   (t reuses h buffer; h dead after edge_kernel)
    dense128<false, true, true><<<N_NODES / 16, 256, 0, stream>>>(agg, Wm1, bm1, h);

    // out = t @ Wm2 + bm2
    dense128<false, true, false><<<N_NODES / 16, 256, 0, stream>>>(h, Wm2, bm2, out);
}

// Round 3
// 932.899 us; speedup vs baseline: 3.4080x; 1.7980x over previous
//
#include <hip/hip_runtime.h>
#include <hip/hip_bf16.h>
#include <math.h>

#define N_NODES 50000
#define N_EDGES 1600000
#define CH 128
#define NF 50

constexpr float DELTA = 5.0f / 49.0f;              // linspace(0,5,50) spacing
constexpr float COEF  = 1.0f / (2.0f * DELTA * DELTA);
constexpr float LOG2_ = 0.6931471805599453f;

typedef short  bf16x8 __attribute__((ext_vector_type(8)));
typedef float  f32x4  __attribute__((ext_vector_type(4)));
typedef unsigned short ushort_t;

// cheap shifted softplus: fmax + exp + log (~7 VALU vs log1pf's ~40)
// abs err vs log1p path < 1e-7 (when exp(-|x|) < 6e-8, log(1+t)=0 vs t: negligible)
__device__ __forceinline__ float ssp(float x) {
    return fmaxf(x, 0.0f) + __logf(1.0f + __expf(-fabsf(x))) - LOG2_;
}

// round-to-nearest-even f32 -> bf16 bits
__device__ __forceinline__ ushort_t f2bf(float x) {
    unsigned u = __float_as_uint(x);
    unsigned r = (u + 0x7fffu + ((u >> 16) & 1u)) >> 16;
    return (ushort_t)r;
}
__device__ __forceinline__ float bf2f(ushort_t u) {
    return __uint_as_float(((unsigned)u) << 16);
}
__device__ __forceinline__ float4 f4zero() { return make_float4(0.f, 0.f, 0.f, 0.f); }

// ---------------------------------------------------------------------------
// Weight prep into bf16 B-fragment layout [n][k] (n = output channel).
//   wf1t : Wf1[k][n] -> [n][k], k padded 50->64, plain bf16
//   wf2  : Wf2[k][n] -> [n][k], hi/lo split
//   wlin : W_lin[n][k] -> [n][k] (y = x @ W^T), hi/lo
//   wm1  : Wm1[k][n] -> [n][k], hi/lo
//   wm2  : Wm2[k][n] -> [n][k], hi/lo
// ---------------------------------------------------------------------------
__global__ __launch_bounds__(256) void prep_weights(const float* __restrict__ Wf1,
                                                    const float* __restrict__ Wf2,
                                                    const float* __restrict__ Wlin,
                                                    const float* __restrict__ Wm1,
                                                    const float* __restrict__ Wm2,
                                                    ushort_t* __restrict__ wf1t,
                                                    ushort_t* __restrict__ wf2hi,
                                                    ushort_t* __restrict__ wf2lo,
                                                    ushort_t* __restrict__ wlhi,
                                                    ushort_t* __restrict__ wllo,
                                                    ushort_t* __restrict__ wm1hi,
                                                    ushort_t* __restrict__ wm1lo,
                                                    ushort_t* __restrict__ wm2hi,
                                                    ushort_t* __restrict__ wm2lo) {
    int idx = blockIdx.x * 256 + threadIdx.x;   // 0..16383
    int n = idx >> 7, k = idx & 127;
    if (k < 64) wf1t[n * 64 + k] = (k < NF) ? f2bf(Wf1[k * CH + n]) : (ushort_t)0;

    {   float w = Wf2[(size_t)k * CH + n];
        ushort_t hi = f2bf(w); wf2hi[n * CH + k] = hi; wf2lo[n * CH + k] = f2bf(w - bf2f(hi)); }
    {   float w = Wlin[(size_t)n * CH + k];
        ushort_t hi = f2bf(w); wlhi[n * CH + k] = hi; wllo[n * CH + k] = f2bf(w - bf2f(hi)); }
    {   float w = Wm1[(size_t)k * CH + n];
        ushort_t hi = f2bf(w); wm1hi[n * CH + k] = hi; wm1lo[n * CH + k] = f2bf(w - bf2f(hi)); }
    {   float w = Wm2[(size_t)k * CH + n];
        ushort_t hi = f2bf(w); wm2hi[n * CH + k] = hi; wm2lo[n * CH + k] = f2bf(w - bf2f(hi)); }
}

// ---------------------------------------------------------------------------
// Counting sort of edges by receiver (unchanged from R2).
// ---------------------------------------------------------------------------
__global__ __launch_bounds__(256) void hist_kernel(const int* __restrict__ recv,
                                                   int* __restrict__ counts) {
    int e = blockIdx.x * 256 + threadIdx.x;
    if (e < N_EDGES) atomicAdd(&counts[recv[e]], 1);
}

__global__ __launch_bounds__(256) void scan1_kernel(const int* __restrict__ counts,
                                                    int* __restrict__ cursor,
                                                    int* __restrict__ bsum) {
    __shared__ int s[256];
    int tid = threadIdx.x;
    int i = blockIdx.x * 256 + tid;
    int v = (i < N_NODES) ? counts[i] : 0;
    s[tid] = v;
    __syncthreads();
    for (int off = 1; off < 256; off <<= 1) {
        int t = (tid >= off) ? s[tid - off] : 0;
        __syncthreads();
        s[tid] += t;
        __syncthreads();
    }
    if (i < N_NODES) cursor[i] = s[tid] - v;
    if (tid == 255) bsum[blockIdx.x] = s[255];
}

__global__ __launch_bounds__(256) void scan2_kernel(int* __restrict__ bsum, int nb) {
    __shared__ int s[256];
    int tid = threadIdx.x;
    int v = (tid < nb) ? bsum[tid] : 0;
    s[tid] = v;
    __syncthreads();
    for (int off = 1; off < 256; off <<= 1) {
        int t = (tid >= off) ? s[tid - off] : 0;
        __syncthreads();
        s[tid] += t;
        __syncthreads();
    }
    if (tid < nb) bsum[tid] = s[tid] - v;
}

__global__ __launch_bounds__(256) void scan3_kernel(int* __restrict__ cursor,
                                                    const int* __restrict__ bsum) {
    int i = blockIdx.x * 256 + threadIdx.x;
    if (i < N_NODES) cursor[i] += bsum[blockIdx.x];
}

__global__ __launch_bounds__(256) void scatter_kernel(const int* __restrict__ recv,
                                                      int* __restrict__ cursor,
                                                      int* __restrict__ perm) {
    int e = blockIdx.x * 256 + threadIdx.x;
    if (e < N_EDGES) {
        int pos = atomicAdd(&cursor[recv[e]], 1);
        perm[pos] = e;
    }
}

// ---------------------------------------------------------------------------
// Dense MFMA: Y = act(X @ B + bias), X [M,128] f32, B prepped bf16 hi/lo in
// [n][k] frag layout. Block 256 thr / 64 rows; wave owns 2 ct x 4 row-tiles.
// 3-term bf16 split => fp32-class accuracy.
// ---------------------------------------------------------------------------
template <bool BIAS, bool ACT>
__global__ __launch_bounds__(256) void dense_mfma(const float* __restrict__ X,
                                                  const ushort_t* __restrict__ Bhi,
                                                  const ushort_t* __restrict__ Blo,
                                                  const float* __restrict__ bias,
                                                  float* __restrict__ Y, int M) {
    __shared__ ushort_t xhi[64][136];
    __shared__ ushort_t xlo[64][136];
    const int tid  = threadIdx.x;
    const int row0 = blockIdx.x * 64;

#pragma unroll
    for (int i = 0; i < 8; i++) {
        int idx = tid + i * 256;            // 0..2047
        int r   = idx >> 5;                 // 0..63
        int c4  = (idx & 31) * 4;
        float4 v = (row0 + r < M) ? *(const float4*)&X[(size_t)(row0 + r) * CH + c4]
                                  : f4zero();
        ushort4 hi, lo;
        hi.x = f2bf(v.x); lo.x = f2bf(v.x - bf2f(hi.x));
        hi.y = f2bf(v.y); lo.y = f2bf(v.y - bf2f(hi.y));
        hi.z = f2bf(v.z); lo.z = f2bf(v.z - bf2f(hi.z));
        hi.w = f2bf(v.w); lo.w = f2bf(v.w - bf2f(hi.w));
        *(ushort4*)&xhi[r][c4] = hi;
        *(ushort4*)&xlo[r][c4] = lo;
    }
    __syncthreads();

    const int lane = tid & 63;
    const int wv   = tid >> 6;
    const int row  = lane & 15;
    const int quad = lane >> 4;
    const int c0   = (2 * wv) * 16 + row;
    const int c1   = c0 + 16;

    f32x4 acc[2][4];
#pragma unroll
    for (int j = 0; j < 2; j++)
#pragma unroll
        for (int rt = 0; rt < 4; rt++) acc[j][rt] = (f32x4){0.f, 0.f, 0.f, 0.f};

#pragma unroll
    for (int kb = 0; kb < 128; kb += 32) {
        bf16x8 B0h = *(const bf16x8*)&Bhi[(size_t)c0 * CH + kb + quad * 8];
        bf16x8 B0l = *(const bf16x8*)&Blo[(size_t)c0 * CH + kb + quad * 8];
        bf16x8 B1h = *(const bf16x8*)&Bhi[(size_t)c1 * CH + kb + quad * 8];
        bf16x8 B1l = *(const bf16x8*)&Blo[(size_t)c1 * CH + kb + quad * 8];
#pragma unroll
        for (int rt = 0; rt < 4; rt++) {
            bf16x8 Ah = *(const bf16x8*)&xhi[rt * 16 + row][kb + quad * 8];
            bf16x8 Al = *(const bf16x8*)&xlo[rt * 16 + row][kb + quad * 8];
            acc[0][rt] = __builtin_amdgcn_mfma_f32_16x16x32_bf16(Al, B0h, acc[0][rt], 0, 0, 0);
            acc[0][rt] = __builtin_amdgcn_mfma_f32_16x16x32_bf16(Ah, B0l, acc[0][rt], 0, 0, 0);
            acc[0][rt] = __builtin_amdgcn_mfma_f32_16x16x32_bf16(Ah, B0h, acc[0][rt], 0, 0, 0);
            acc[1][rt] = __builtin_amdgcn_mfma_f32_16x16x32_bf16(Al, B1h, acc[1][rt], 0, 0, 0);
            acc[1][rt] = __builtin_amdgcn_mfma_f32_16x16x32_bf16(Ah, B1l, acc[1][rt], 0, 0, 0);
            acc[1][rt] = __builtin_amdgcn_mfma_f32_16x16x32_bf16(Ah, B1h, acc[1][rt], 0, 0, 0);
        }
    }

    float bv[2];
    bv[0] = BIAS ? bias[c0] : 0.f;
    bv[1] = BIAS ? bias[c1] : 0.f;
#pragma unroll
    for (int j = 0; j < 2; j++) {
        int c = j ? c1 : c0;
#pragma unroll
        for (int rt = 0; rt < 4; rt++)
#pragma unroll
            for (int rg = 0; rg < 4; rg++) {
                int r = row0 + rt * 16 + quad * 4 + rg;
                if (r < M) {
                    float v = acc[j][rt][rg] + bv[j];
                    if (ACT) v = ssp(v);
                    Y[(size_t)r * CH + c] = v;
                }
            }
    }
}

// ---------------------------------------------------------------------------
// Fused edge kernel over receiver-sorted edges. Block 256 thr, 64 edges.
// ct-split: wave w owns channels [2w*16, 2w*16+32) for ALL 64 edges
// (4 row-tiles) => B-fragment global loads amortized 4x vs per-wave-all-ct.
// ---------------------------------------------------------------------------
__global__ __launch_bounds__(256) void edge_kernel(const float* __restrict__ dist,
                                                   const int* __restrict__ senders,
                                                   const int* __restrict__ receivers,
                                                   const int* __restrict__ perm,
                                                   const ushort_t* __restrict__ wf1t,
                                                   const float* __restrict__ bf1,
                                                   const ushort_t* __restrict__ wf2hi,
                                                   const ushort_t* __restrict__ wf2lo,
                                                   const float* __restrict__ bf2,
                                                   const float* __restrict__ h,
                                                   float* __restrict__ agg) {
    __shared__ ushort_t basis[64][72];
    __shared__ ushort_t t1hi[64][136];
    __shared__ ushort_t t1lo[64][136];
    __shared__ float aggS[16][128];
    __shared__ float dist_s[64];
    __shared__ int r_s[64], sid_s[64], slot_s[64], slotr_s[16];
    __shared__ int nslots_s;

    const int tid = threadIdx.x;
    const int e0  = blockIdx.x * 64;

    if (tid < 64) {
        int eid = perm[e0 + tid];
        dist_s[tid] = dist[eid];
        r_s[tid]    = receivers[eid];
        sid_s[tid]  = senders[eid];
    }
    for (int i = tid; i < 16 * 128; i += 256) ((float*)aggS)[i] = 0.f;
    __syncthreads();

    // slot = rank of distinct receiver within block (wave 0)
    if (tid < 64) {
        int lane = tid;
        int flag = (lane > 0 && r_s[lane] != r_s[lane - 1]) ? 1 : 0;
        int v = flag;
        for (int off = 1; off < 64; off <<= 1) {
            int u = __shfl_up(v, off);
            if (lane >= off) v += u;
        }
        slot_s[lane] = v;
        if ((flag || lane == 0) && v < 16) slotr_s[v] = r_s[lane];
        if (lane == 63) nslots_s = v + 1;
    }
    // Gaussian basis -> bf16 LDS (k padded to 64)
    for (int i = tid; i < 64 * 64; i += 256) {
        int e = i >> 6, k = i & 63;
        float val = 0.f;
        if (k < NF) {
            float d = dist_s[e] - (float)k * DELTA;
            val = __expf(-COEF * d * d);
        }
        basis[e][k] = f2bf(val);
    }
    __syncthreads();

    const int lane = tid & 63;
    const int wv   = tid >> 6;
    const int row  = lane & 15;
    const int quad = lane >> 4;
    const int c0   = (2 * wv) * 16 + row;
    const int c1   = c0 + 16;

    f32x4 acc[2][4];
#pragma unroll
    for (int j = 0; j < 2; j++)
#pragma unroll
        for (int rt = 0; rt < 4; rt++) acc[j][rt] = (f32x4){0.f, 0.f, 0.f, 0.f};

    // ---- GEMM1: t1 = ssp(basis @ Wf1 + bf1) ----
#pragma unroll
    for (int kb = 0; kb < 64; kb += 32) {
        bf16x8 B0 = *(const bf16x8*)&wf1t[c0 * 64 + kb + quad * 8];
        bf16x8 B1 = *(const bf16x8*)&wf1t[c1 * 64 + kb + quad * 8];
#pragma unroll
        for (int rt = 0; rt < 4; rt++) {
            bf16x8 A = *(const bf16x8*)&basis[rt * 16 + row][kb + quad * 8];
            acc[0][rt] = __builtin_amdgcn_mfma_f32_16x16x32_bf16(A, B0, acc[0][rt], 0, 0, 0);
            acc[1][rt] = __builtin_amdgcn_mfma_f32_16x16x32_bf16(A, B1, acc[1][rt], 0, 0, 0);
        }
    }
    {
        float b1v0 = bf1[c0], b1v1 = bf1[c1];
#pragma unroll
        for (int j = 0; j < 2; j++) {
            int c = j ? c1 : c0;
            float bb = j ? b1v1 : b1v0;
#pragma unroll
            for (int rt = 0; rt < 4; rt++)
#pragma unroll
                for (int rg = 0; rg < 4; rg++) {
                    int e = rt * 16 + quad * 4 + rg;
                    float t = ssp(acc[j][rt][rg] + bb);
                    ushort_t hi = f2bf(t);
                    t1hi[e][c] = hi;
                    t1lo[e][c] = f2bf(t - bf2f(hi));
                }
        }
    }
    __syncthreads();

    // ---- GEMM2: ef = t1 @ Wf2 + bf2 (3-term bf16 split) ----
#pragma unroll
    for (int j = 0; j < 2; j++)
#pragma unroll
        for (int rt = 0; rt < 4; rt++) acc[j][rt] = (f32x4){0.f, 0.f, 0.f, 0.f};

#pragma unroll
    for (int kb = 0; kb < 128; kb += 32) {
        bf16x8 B0h = *(const bf16x8*)&wf2hi[c0 * CH + kb + quad * 8];
        bf16x8 B0l = *(const bf16x8*)&wf2lo[c0 * CH + kb + quad * 8];
        bf16x8 B1h = *(const bf16x8*)&wf2hi[c1 * CH + kb + quad * 8];
        bf16x8 B1l = *(const bf16x8*)&wf2lo[c1 * CH + kb + quad * 8];
#pragma unroll
        for (int rt = 0; rt < 4; rt++) {
            bf16x8 Ah = *(const bf16x8*)&t1hi[rt * 16 + row][kb + quad * 8];
            bf16x8 Al = *(const bf16x8*)&t1lo[rt * 16 + row][kb + quad * 8];
            acc[0][rt] = __builtin_amdgcn_mfma_f32_16x16x32_bf16(Al, B0h, acc[0][rt], 0, 0, 0);
            acc[0][rt] = __builtin_amdgcn_mfma_f32_16x16x32_bf16(Ah, B0l, acc[0][rt], 0, 0, 0);
            acc[0][rt] = __builtin_amdgcn_mfma_f32_16x16x32_bf16(Ah, B0h, acc[0][rt], 0, 0, 0);
            acc[1][rt] = __builtin_amdgcn_mfma_f32_16x16x32_bf16(Al, B1h, acc[1][rt], 0, 0, 0);
            acc[1][rt] = __builtin_amdgcn_mfma_f32_16x16x32_bf16(Ah, B1l, acc[1][rt], 0, 0, 0);
            acc[1][rt] = __builtin_amdgcn_mfma_f32_16x16x32_bf16(Ah, B1h, acc[1][rt], 0, 0, 0);
        }
    }

    // ---- epilogue: message = h[sender]*ef, slot aggregation ----
    float b2v[2] = { bf2[c0], bf2[c1] };
#pragma unroll
    for (int rt = 0; rt < 4; rt++) {
        const int eb   = rt * 16;
        const int slt0 = slot_s[eb];
        const int r0   = r_s[eb];
        const bool tileuni = (slt0 == slot_s[eb + 15]);   // whole 16-edge tile one receiver
        const int et = eb + quad * 4;
        int sid[4];
#pragma unroll
        for (int rg = 0; rg < 4; rg++) sid[rg] = sid_s[et + rg];

#pragma unroll
        for (int j = 0; j < 2; j++) {
            int c = j ? c1 : c0;
            float m[4];
#pragma unroll
            for (int rg = 0; rg < 4; rg++)
                m[rg] = h[(size_t)sid[rg] * CH + c] * (acc[j][rt][rg] + b2v[j]);

            if (tileuni) {
                // reduce 16 edges across rg + quads; one atomic from quad 0
                float s = (m[0] + m[1]) + (m[2] + m[3]);
                s += __shfl_xor(s, 16);
                s += __shfl_xor(s, 32);
                if (quad == 0) {
                    if (slt0 < 16) atomicAdd(&aggS[slt0][c], s);
                    else           unsafeAtomicAdd(&agg[(size_t)r0 * CH + c], s);
                }
            } else {
                int sq0 = slot_s[et], sq3 = slot_s[et + 3];
                if (sq0 == sq3) {
                    float s = (m[0] + m[1]) + (m[2] + m[3]);
                    if (sq0 < 16) atomicAdd(&aggS[sq0][c], s);
                    else          unsafeAtomicAdd(&agg[(size_t)r_s[et] * CH + c], s);
                } else {
#pragma unroll
                    for (int rg = 0; rg < 4; rg++) {
                        int sl = slot_s[et + rg];
                        if (sl < 16) atomicAdd(&aggS[sl][c], m[rg]);
                        else         unsafeAtomicAdd(&agg[(size_t)r_s[et + rg] * CH + c], m[rg]);
                    }
                }
            }
        }
    }
    __syncthreads();

    // flush slots -> global
    int ns = nslots_s < 16 ? nslots_s : 16;
    for (int i = tid; i < ns * 128; i += 256) {
        int s = i >> 7, c = i & 127;
        unsafeAtomicAdd(&agg[(size_t)slotr_s[s] * CH + c], aggS[s][c]);
    }
}

// ---------------------------------------------------------------------------
extern "C" void kernel_launch(void* const* d_in, const int* in_sizes, int n_in,
                              void* d_out, int out_size, void* d_ws, size_t ws_size,
                              hipStream_t stream) {
    const float* features = (const float*)d_in[0];
    const float* dist     = (const float*)d_in[1];
    const float* W_lin    = (const float*)d_in[2];
    const float* Wf1      = (const float*)d_in[3];
    const float* bf1      = (const float*)d_in[4];
    const float* Wf2      = (const float*)d_in[5];
    const float* bf2      = (const float*)d_in[6];
    const float* Wm1      = (const float*)d_in[7];
    const float* bm1      = (const float*)d_in[8];
    const float* Wm2      = (const float*)d_in[9];
    const float* bm2      = (const float*)d_in[10];
    const int* senders    = (const int*)d_in[11];
    const int* receivers  = (const int*)d_in[12];
    float* out = (float*)d_out;

    // workspace layout (~33 MB)
    float* h       = (float*)d_ws;                         // [N,128] f32, reused as t
    int*   perm    = (int*)(h + (size_t)N_NODES * CH);     // [E]
    int*   counts  = perm + N_EDGES;                       // [N]
    int*   cursor  = counts + N_NODES;                     // [N]
    int*   bsum    = cursor + N_NODES;                     // [256]
    ushort_t* wf1t  = (ushort_t*)(bsum + 256);             // [128*64]
    ushort_t* wf2hi = wf1t + 128 * 64;
    ushort_t* wf2lo = wf2hi + 128 * 128;
    ushort_t* wlhi  = wf2lo + 128 * 128;
    ushort_t* wllo  = wlhi + 128 * 128;
    ushort_t* wm1hi = wllo + 128 * 128;
    ushort_t* wm1lo = wm1hi + 128 * 128;
    ushort_t* wm2hi = wm1lo + 128 * 128;
    ushort_t* wm2lo = wm2hi + 128 * 128;

    float* agg = out;   // accumulate segment-sum directly in d_out

    hipMemsetAsync(counts, 0, (size_t)N_NODES * sizeof(int), stream);
    hipMemsetAsync(agg, 0, (size_t)N_NODES * CH * sizeof(float), stream);

    prep_weights<<<64, 256, 0, stream>>>(Wf1, Wf2, W_lin, Wm1, Wm2,
                                         wf1t, wf2hi, wf2lo, wlhi, wllo,
                                         wm1hi, wm1lo, wm2hi, wm2lo);

    const int nb_scan = (N_NODES + 255) / 256;   // 196
    hist_kernel<<<(N_EDGES + 255) / 256, 256, 0, stream>>>(receivers, counts);
    scan1_kernel<<<nb_scan, 256, 0, stream>>>(counts, cursor, bsum);
    scan2_kernel<<<1, 256, 0, stream>>>(bsum, nb_scan);
    scan3_kernel<<<nb_scan, 256, 0, stream>>>(cursor, bsum);
    scatter_kernel<<<(N_EDGES + 255) / 256, 256, 0, stream>>>(receivers, cursor, perm);

    const int nb_dense = (N_NODES + 63) / 64;    // 782

    // h = features @ W_lin^T
    dense_mfma<false, false><<<nb_dense, 256, 0, stream>>>(features, wlhi, wllo, nullptr, h, N_NODES);

    // fused edge pipeline (sorted) -> agg (= d_out)
    edge_kernel<<<N_EDGES / 64, 256, 0, stream>>>(dist, senders, receivers, perm,
                                                  wf1t, bf1, wf2hi, wf2lo, bf2, h, agg);

    // t = ssp(agg @ Wm1 + bm1)   (t reuses h buffer)
    dense_mfma<true, true><<<nb_dense, 256, 0, stream>>>(agg, wm1hi, wm1lo, bm1, h, N_NODES);

    // out = t @ Wm2 + bm2
    dense_mfma<true, false><<<nb_dense, 256, 0, stream>>>(h, wm2hi, wm2lo, bm2, out, N_NODES);
}

// Round 4
// 802.334 us; speedup vs baseline: 3.9626x; 1.1627x over previous
//
#include <hip/hip_runtime.h>
#include <hip/hip_bf16.h>
#include <math.h>

#define N_NODES 50000
#define N_EDGES 1600000
#define CH 128
#define NF 50

constexpr float DELTA = 5.0f / 49.0f;              // linspace(0,5,50) spacing
constexpr float COEF  = 1.0f / (2.0f * DELTA * DELTA);
constexpr float LOG2_ = 0.6931471805599453f;

typedef short  bf16x8 __attribute__((ext_vector_type(8)));
typedef float  f32x4  __attribute__((ext_vector_type(4)));
typedef unsigned short ushort_t;

// cheap shifted softplus
__device__ __forceinline__ float ssp(float x) {
    return fmaxf(x, 0.0f) + __logf(1.0f + __expf(-fabsf(x))) - LOG2_;
}

// HW bf16 convert (v_cvt, RNE) — 1 instr vs 4-op manual sequence
__device__ __forceinline__ ushort_t f2bf(float x) {
    __hip_bfloat16 b = __float2bfloat16(x);
    return *reinterpret_cast<ushort_t*>(&b);
}
__device__ __forceinline__ float bf2f(ushort_t u) {
    return __uint_as_float(((unsigned)u) << 16);
}
__device__ __forceinline__ float4 f4zero() { return make_float4(0.f, 0.f, 0.f, 0.f); }

// ---------------------------------------------------------------------------
// Weight prep into bf16 B-fragment layout [n][k] (n = output channel), hi/lo.
// ---------------------------------------------------------------------------
__global__ __launch_bounds__(256) void prep_weights(const float* __restrict__ Wf1,
                                                    const float* __restrict__ Wf2,
                                                    const float* __restrict__ Wlin,
                                                    const float* __restrict__ Wm1,
                                                    const float* __restrict__ Wm2,
                                                    ushort_t* __restrict__ wf1t,
                                                    ushort_t* __restrict__ wf2hi,
                                                    ushort_t* __restrict__ wf2lo,
                                                    ushort_t* __restrict__ wlhi,
                                                    ushort_t* __restrict__ wllo,
                                                    ushort_t* __restrict__ wm1hi,
                                                    ushort_t* __restrict__ wm1lo,
                                                    ushort_t* __restrict__ wm2hi,
                                                    ushort_t* __restrict__ wm2lo) {
    int idx = blockIdx.x * 256 + threadIdx.x;   // 0..16383
    int n = idx >> 7, k = idx & 127;
    if (k < 64) wf1t[n * 64 + k] = (k < NF) ? f2bf(Wf1[k * CH + n]) : (ushort_t)0;

    {   float w = Wf2[(size_t)k * CH + n];
        ushort_t hi = f2bf(w); wf2hi[n * CH + k] = hi; wf2lo[n * CH + k] = f2bf(w - bf2f(hi)); }
    {   float w = Wlin[(size_t)n * CH + k];
        ushort_t hi = f2bf(w); wlhi[n * CH + k] = hi; wllo[n * CH + k] = f2bf(w - bf2f(hi)); }
    {   float w = Wm1[(size_t)k * CH + n];
        ushort_t hi = f2bf(w); wm1hi[n * CH + k] = hi; wm1lo[n * CH + k] = f2bf(w - bf2f(hi)); }
    {   float w = Wm2[(size_t)k * CH + n];
        ushort_t hi = f2bf(w); wm2hi[n * CH + k] = hi; wm2lo[n * CH + k] = f2bf(w - bf2f(hi)); }
}

// ---------------------------------------------------------------------------
// Counting sort of edges by receiver.
// ---------------------------------------------------------------------------
__global__ __launch_bounds__(256) void hist_kernel(const int* __restrict__ recv,
                                                   int* __restrict__ counts) {
    int e = blockIdx.x * 256 + threadIdx.x;
    if (e < N_EDGES) atomicAdd(&counts[recv[e]], 1);
}

__global__ __launch_bounds__(256) void scan1_kernel(const int* __restrict__ counts,
                                                    int* __restrict__ cursor,
                                                    int* __restrict__ bsum) {
    __shared__ int s[256];
    int tid = threadIdx.x;
    int i = blockIdx.x * 256 + tid;
    int v = (i < N_NODES) ? counts[i] : 0;
    s[tid] = v;
    __syncthreads();
    for (int off = 1; off < 256; off <<= 1) {
        int t = (tid >= off) ? s[tid - off] : 0;
        __syncthreads();
        s[tid] += t;
        __syncthreads();
    }
    if (i < N_NODES) cursor[i] = s[tid] - v;
    if (tid == 255) bsum[blockIdx.x] = s[255];
}

__global__ __launch_bounds__(256) void scan2_kernel(int* __restrict__ bsum, int nb) {
    __shared__ int s[256];
    int tid = threadIdx.x;
    int v = (tid < nb) ? bsum[tid] : 0;
    s[tid] = v;
    __syncthreads();
    for (int off = 1; off < 256; off <<= 1) {
        int t = (tid >= off) ? s[tid - off] : 0;
        __syncthreads();
        s[tid] += t;
        __syncthreads();
    }
    if (tid < nb) bsum[tid] = s[tid] - v;
}

__global__ __launch_bounds__(256) void scan3_kernel(int* __restrict__ cursor,
                                                    const int* __restrict__ bsum) {
    int i = blockIdx.x * 256 + threadIdx.x;
    if (i < N_NODES) cursor[i] += bsum[blockIdx.x];
}

__global__ __launch_bounds__(256) void scatter_kernel(const int* __restrict__ recv,
                                                      int* __restrict__ cursor,
                                                      int* __restrict__ perm) {
    int e = blockIdx.x * 256 + threadIdx.x;
    if (e < N_EDGES) {
        int pos = atomicAdd(&cursor[recv[e]], 1);
        perm[pos] = e;
    }
}

// ---------------------------------------------------------------------------
// Dense MFMA: Y = act(X @ B + bias). X staged as plain bf16; B hi/lo 2-term
// (X-rounding err ~0.2% rel — within budget).
// ---------------------------------------------------------------------------
template <bool BIAS, bool ACT>
__global__ __launch_bounds__(256) void dense_mfma(const float* __restrict__ X,
                                                  const ushort_t* __restrict__ Bhi,
                                                  const ushort_t* __restrict__ Blo,
                                                  const float* __restrict__ bias,
                                                  float* __restrict__ Y, int M) {
    __shared__ ushort_t xs[64][136];
    const int tid  = threadIdx.x;
    const int row0 = blockIdx.x * 64;

#pragma unroll
    for (int i = 0; i < 8; i++) {
        int idx = tid + i * 256;            // 0..2047
        int r   = idx >> 5;                 // 0..63
        int c4  = (idx & 31) * 4;
        float4 v = (row0 + r < M) ? *(const float4*)&X[(size_t)(row0 + r) * CH + c4]
                                  : f4zero();
        ushort4 s;
        s.x = f2bf(v.x); s.y = f2bf(v.y); s.z = f2bf(v.z); s.w = f2bf(v.w);
        *(ushort4*)&xs[r][c4] = s;
    }
    __syncthreads();

    const int lane = tid & 63;
    const int wv   = tid >> 6;
    const int row  = lane & 15;
    const int quad = lane >> 4;
    const int c0   = (2 * wv) * 16 + row;
    const int c1   = c0 + 16;

    f32x4 acc[2][4];
#pragma unroll
    for (int j = 0; j < 2; j++)
#pragma unroll
        for (int rt = 0; rt < 4; rt++) acc[j][rt] = (f32x4){0.f, 0.f, 0.f, 0.f};

#pragma unroll
    for (int kb = 0; kb < 128; kb += 32) {
        bf16x8 B0h = *(const bf16x8*)&Bhi[(size_t)c0 * CH + kb + quad * 8];
        bf16x8 B0l = *(const bf16x8*)&Blo[(size_t)c0 * CH + kb + quad * 8];
        bf16x8 B1h = *(const bf16x8*)&Bhi[(size_t)c1 * CH + kb + quad * 8];
        bf16x8 B1l = *(const bf16x8*)&Blo[(size_t)c1 * CH + kb + quad * 8];
#pragma unroll
        for (int rt = 0; rt < 4; rt++) {
            bf16x8 A = *(const bf16x8*)&xs[rt * 16 + row][kb + quad * 8];
            acc[0][rt] = __builtin_amdgcn_mfma_f32_16x16x32_bf16(A, B0l, acc[0][rt], 0, 0, 0);
            acc[0][rt] = __builtin_amdgcn_mfma_f32_16x16x32_bf16(A, B0h, acc[0][rt], 0, 0, 0);
            acc[1][rt] = __builtin_amdgcn_mfma_f32_16x16x32_bf16(A, B1l, acc[1][rt], 0, 0, 0);
            acc[1][rt] = __builtin_amdgcn_mfma_f32_16x16x32_bf16(A, B1h, acc[1][rt], 0, 0, 0);
        }
    }

    float bv[2];
    bv[0] = BIAS ? bias[c0] : 0.f;
    bv[1] = BIAS ? bias[c1] : 0.f;
#pragma unroll
    for (int j = 0; j < 2; j++) {
        int c = j ? c1 : c0;
#pragma unroll
        for (int rt = 0; rt < 4; rt++)
#pragma unroll
            for (int rg = 0; rg < 4; rg++) {
                int r = row0 + rt * 16 + quad * 4 + rg;
                if (r < M) {
                    float v = acc[j][rt][rg] + bv[j];
                    if (ACT) v = ssp(v);
                    Y[(size_t)r * CH + c] = v;
                }
            }
    }
}

// ---------------------------------------------------------------------------
// Fused edge kernel over receiver-sorted edges. Block 256 thr / 4 waves,
// 64 edges. Wave owns 2 channel-tiles x all 4 row-tiles.
// GEMM2 2-term (t1 plain bf16, Wf2 hi/lo). h-gather hoisted before the
// GEMM1 epilogue so its latency hides under ssp + barrier drain.
// ---------------------------------------------------------------------------
__global__ __launch_bounds__(256, 4) void edge_kernel(const float* __restrict__ dist,
                                                      const int* __restrict__ senders,
                                                      const int* __restrict__ receivers,
                                                      const int* __restrict__ perm,
                                                      const ushort_t* __restrict__ wf1t,
                                                      const float* __restrict__ bf1,
                                                      const ushort_t* __restrict__ wf2hi,
                                                      const ushort_t* __restrict__ wf2lo,
                                                      const float* __restrict__ bf2,
                                                      const float* __restrict__ h,
                                                      float* __restrict__ agg) {
    __shared__ ushort_t basis[64][72];
    __shared__ ushort_t t1s[64][136];
    __shared__ float aggS[16][128];
    __shared__ float dist_s[64];
    __shared__ int r_s[64], sid_s[64], slot_s[64], slotr_s[16];
    __shared__ int nslots_s;

    const int tid = threadIdx.x;
    const int e0  = blockIdx.x * 64;

    if (tid < 64) {
        int eid = perm[e0 + tid];
        dist_s[tid] = dist[eid];
        r_s[tid]    = receivers[eid];
        sid_s[tid]  = senders[eid];
    }
    {   // zero aggS with float4 stores (2 per thread)
        float4 z = f4zero();
        float* a = (float*)aggS + tid * 8;
        *(float4*)(a + 0) = z;
        *(float4*)(a + 4) = z;
    }
    __syncthreads();

    // slot = rank of distinct receiver within block (wave 0)
    if (tid < 64) {
        int lane = tid;
        int flag = (lane > 0 && r_s[lane] != r_s[lane - 1]) ? 1 : 0;
        int v = flag;
        for (int off = 1; off < 64; off <<= 1) {
            int u = __shfl_up(v, off);
            if (lane >= off) v += u;
        }
        slot_s[lane] = v;
        if ((flag || lane == 0) && v < 16) slotr_s[v] = r_s[lane];
        if (lane == 63) nslots_s = v + 1;
    }
    // Gaussian basis -> bf16 LDS (k padded to 64)
    for (int i = tid; i < 64 * 64; i += 256) {
        int e = i >> 6, k = i & 63;
        float val = 0.f;
        if (k < NF) {
            float d = dist_s[e] - (float)k * DELTA;
            val = __expf(-COEF * d * d);
        }
        basis[e][k] = f2bf(val);
    }
    __syncthreads();

    const int lane = tid & 63;
    const int wv   = tid >> 6;
    const int row  = lane & 15;
    const int quad = lane >> 4;
    const int c0   = (2 * wv) * 16 + row;
    const int c1   = c0 + 16;

    f32x4 acc[2][4];
#pragma unroll
    for (int j = 0; j < 2; j++)
#pragma unroll
        for (int rt = 0; rt < 4; rt++) acc[j][rt] = (f32x4){0.f, 0.f, 0.f, 0.f};

    // ---- GEMM1: t1 = ssp(basis @ Wf1 + bf1) ----
#pragma unroll
    for (int kb = 0; kb < 64; kb += 32) {
        bf16x8 B0 = *(const bf16x8*)&wf1t[c0 * 64 + kb + quad * 8];
        bf16x8 B1 = *(const bf16x8*)&wf1t[c1 * 64 + kb + quad * 8];
#pragma unroll
        for (int rt = 0; rt < 4; rt++) {
            bf16x8 A = *(const bf16x8*)&basis[rt * 16 + row][kb + quad * 8];
            acc[0][rt] = __builtin_amdgcn_mfma_f32_16x16x32_bf16(A, B0, acc[0][rt], 0, 0, 0);
            acc[1][rt] = __builtin_amdgcn_mfma_f32_16x16x32_bf16(A, B1, acc[1][rt], 0, 0, 0);
        }
    }

    // ---- hoist h-gather: latency overlaps ssp epilogue + barrier drain ----
    float hv[4][4][2];
#pragma unroll
    for (int rt = 0; rt < 4; rt++)
#pragma unroll
        for (int rg = 0; rg < 4; rg++) {
            int s = sid_s[rt * 16 + quad * 4 + rg];
            const float* hp = &h[(size_t)s * CH];
            hv[rt][rg][0] = hp[c0];
            hv[rt][rg][1] = hp[c1];
        }

    // ---- GEMM1 epilogue: bias + ssp -> plain bf16 t1 ----
    {
        float b1v[2] = { bf1[c0], bf1[c1] };
#pragma unroll
        for (int j = 0; j < 2; j++) {
            int c = j ? c1 : c0;
#pragma unroll
            for (int rt = 0; rt < 4; rt++)
#pragma unroll
                for (int rg = 0; rg < 4; rg++) {
                    int e = rt * 16 + quad * 4 + rg;
                    t1s[e][c] = f2bf(ssp(acc[j][rt][rg] + b1v[j]));
                }
        }
    }
    __syncthreads();

    // ---- GEMM2: ef = t1 @ Wf2 + bf2 (2-term: A plain, B hi/lo) ----
#pragma unroll
    for (int j = 0; j < 2; j++)
#pragma unroll
        for (int rt = 0; rt < 4; rt++) acc[j][rt] = (f32x4){0.f, 0.f, 0.f, 0.f};

#pragma unroll
    for (int kb = 0; kb < 128; kb += 32) {
        bf16x8 B0h = *(const bf16x8*)&wf2hi[c0 * CH + kb + quad * 8];
        bf16x8 B0l = *(const bf16x8*)&wf2lo[c0 * CH + kb + quad * 8];
        bf16x8 B1h = *(const bf16x8*)&wf2hi[c1 * CH + kb + quad * 8];
        bf16x8 B1l = *(const bf16x8*)&wf2lo[c1 * CH + kb + quad * 8];
#pragma unroll
        for (int rt = 0; rt < 4; rt++) {
            bf16x8 A = *(const bf16x8*)&t1s[rt * 16 + row][kb + quad * 8];
            acc[0][rt] = __builtin_amdgcn_mfma_f32_16x16x32_bf16(A, B0l, acc[0][rt], 0, 0, 0);
            acc[0][rt] = __builtin_amdgcn_mfma_f32_16x16x32_bf16(A, B0h, acc[0][rt], 0, 0, 0);
            acc[1][rt] = __builtin_amdgcn_mfma_f32_16x16x32_bf16(A, B1l, acc[1][rt], 0, 0, 0);
            acc[1][rt] = __builtin_amdgcn_mfma_f32_16x16x32_bf16(A, B1h, acc[1][rt], 0, 0, 0);
        }
    }

    // ---- epilogue: message = h[sender]*ef, slot aggregation ----
    float b2v[2] = { bf2[c0], bf2[c1] };
#pragma unroll
    for (int rt = 0; rt < 4; rt++) {
        const int eb   = rt * 16;
        const int slt0 = slot_s[eb];
        const int r0   = r_s[eb];
        const bool tileuni = (slt0 == slot_s[eb + 15]);
        const int et = eb + quad * 4;

#pragma unroll
        for (int j = 0; j < 2; j++) {
            int c = j ? c1 : c0;
            float m[4];
#pragma unroll
            for (int rg = 0; rg < 4; rg++)
                m[rg] = hv[rt][rg][j] * (acc[j][rt][rg] + b2v[j]);

            if (tileuni) {
                float s = (m[0] + m[1]) + (m[2] + m[3]);
                s += __shfl_xor(s, 16);
                s += __shfl_xor(s, 32);
                if (quad == 0) {
                    if (slt0 < 16) atomicAdd(&aggS[slt0][c], s);
                    else           unsafeAtomicAdd(&agg[(size_t)r0 * CH + c], s);
                }
            } else {
                int sq0 = slot_s[et], sq3 = slot_s[et + 3];
                if (sq0 == sq3) {
                    float s = (m[0] + m[1]) + (m[2] + m[3]);
                    if (sq0 < 16) atomicAdd(&aggS[sq0][c], s);
                    else          unsafeAtomicAdd(&agg[(size_t)r_s[et] * CH + c], s);
                } else {
#pragma unroll
                    for (int rg = 0; rg < 4; rg++) {
                        int sl = slot_s[et + rg];
                        if (sl < 16) atomicAdd(&aggS[sl][c], m[rg]);
                        else         unsafeAtomicAdd(&agg[(size_t)r_s[et + rg] * CH + c], m[rg]);
                    }
                }
            }
        }
    }
    __syncthreads();

    // flush slots -> global
    int ns = nslots_s < 16 ? nslots_s : 16;
    for (int i = tid; i < ns * 128; i += 256) {
        int s = i >> 7, c = i & 127;
        unsafeAtomicAdd(&agg[(size_t)slotr_s[s] * CH + c], aggS[s][c]);
    }
}

// ---------------------------------------------------------------------------
extern "C" void kernel_launch(void* const* d_in, const int* in_sizes, int n_in,
                              void* d_out, int out_size, void* d_ws, size_t ws_size,
                              hipStream_t stream) {
    const float* features = (const float*)d_in[0];
    const float* dist     = (const float*)d_in[1];
    const float* W_lin    = (const float*)d_in[2];
    const float* Wf1      = (const float*)d_in[3];
    const float* bf1      = (const float*)d_in[4];
    const float* Wf2      = (const float*)d_in[5];
    const float* bf2      = (const float*)d_in[6];
    const float* Wm1      = (const float*)d_in[7];
    const float* bm1      = (const float*)d_in[8];
    const float* Wm2      = (const float*)d_in[9];
    const float* bm2      = (const float*)d_in[10];
    const int* senders    = (const int*)d_in[11];
    const int* receivers  = (const int*)d_in[12];
    float* out = (float*)d_out;

    // workspace layout (~33 MB)
    float* h       = (float*)d_ws;                         // [N,128] f32, reused as t
    int*   perm    = (int*)(h + (size_t)N_NODES * CH);     // [E]
    int*   counts  = perm + N_EDGES;                       // [N]
    int*   cursor  = counts + N_NODES;                     // [N]
    int*   bsum    = cursor + N_NODES;                     // [256]
    ushort_t* wf1t  = (ushort_t*)(bsum + 256);             // [128*64]
    ushort_t* wf2hi = wf1t + 128 * 64;
    ushort_t* wf2lo = wf2hi + 128 * 128;
    ushort_t* wlhi  = wf2lo + 128 * 128;
    ushort_t* wllo  = wlhi + 128 * 128;
    ushort_t* wm1hi = wllo + 128 * 128;
    ushort_t* wm1lo = wm1hi + 128 * 128;
    ushort_t* wm2hi = wm1lo + 128 * 128;
    ushort_t* wm2lo = wm2hi + 128 * 128;

    float* agg = out;   // accumulate segment-sum directly in d_out

    hipMemsetAsync(counts, 0, (size_t)N_NODES * sizeof(int), stream);
    hipMemsetAsync(agg, 0, (size_t)N_NODES * CH * sizeof(float), stream);

    prep_weights<<<64, 256, 0, stream>>>(Wf1, Wf2, W_lin, Wm1, Wm2,
                                         wf1t, wf2hi, wf2lo, wlhi, wllo,
                                         wm1hi, wm1lo, wm2hi, wm2lo);

    const int nb_scan = (N_NODES + 255) / 256;   // 196
    hist_kernel<<<(N_EDGES + 255) / 256, 256, 0, stream>>>(receivers, counts);
    scan1_kernel<<<nb_scan, 256, 0, stream>>>(counts, cursor, bsum);
    scan2_kernel<<<1, 256, 0, stream>>>(bsum, nb_scan);
    scan3_kernel<<<nb_scan, 256, 0, stream>>>(cursor, bsum);
    scatter_kernel<<<(N_EDGES + 255) / 256, 256, 0, stream>>>(receivers, cursor, perm);

    const int nb_dense = (N_NODES + 63) / 64;    // 782

    // h = features @ W_lin^T
    dense_mfma<false, false><<<nb_dense, 256, 0, stream>>>(features, wlhi, wllo, nullptr, h, N_NODES);

    // fused edge pipeline (sorted) -> agg (= d_out)
    edge_kernel<<<N_EDGES / 64, 256, 0, stream>>>(dist, senders, receivers, perm,
                                                  wf1t, bf1, wf2hi, wf2lo, bf2, h, agg);

    // t = ssp(agg @ Wm1 + bm1)   (t reuses h buffer)
    dense_mfma<true, true><<<nb_dense, 256, 0, stream>>>(agg, wm1hi, wm1lo, bm1, h, N_NODES);

    // out = t @ Wm2 + bm2
    dense_mfma<true, false><<<nb_dense, 256, 0, stream>>>(h, wm2hi, wm2lo, bm2, out, N_NODES);
}

// Round 5
// 468.020 us; speedup vs baseline: 6.7932x; 1.7143x over previous
//
#include <hip/hip_runtime.h>
#include <hip/hip_bf16.h>
#include <math.h>

#define N_NODES 50000
#define N_EDGES 1600000
#define CH 128
#define NF 50
#define NR 4096            // ef(r) table resolution
#define NODES_PER_BLK 8
#define CHUNK 1024

constexpr float DELTA  = 5.0f / 49.0f;             // linspace(0,5,50) spacing
constexpr float COEF   = 1.0f / (2.0f * DELTA * DELTA);
constexpr float LOG2_  = 0.6931471805599453f;
constexpr float RSCALE = (float)(NR - 1) / 5.0f;   // r -> grid coordinate

typedef short  bf16x8 __attribute__((ext_vector_type(8)));
typedef float  f32x4  __attribute__((ext_vector_type(4)));
typedef unsigned short ushort_t;

__device__ __forceinline__ float ssp(float x) {
    return fmaxf(x, 0.0f) + __logf(1.0f + __expf(-fabsf(x))) - LOG2_;
}
__device__ __forceinline__ ushort_t f2bf(float x) {
    __hip_bfloat16 b = __float2bfloat16(x);
    return *reinterpret_cast<ushort_t*>(&b);
}
__device__ __forceinline__ float bf2f(ushort_t u) {
    return __uint_as_float(((unsigned)u) << 16);
}
__device__ __forceinline__ float4 f4zero() { return make_float4(0.f, 0.f, 0.f, 0.f); }

// ---------------------------------------------------------------------------
// Weight prep: node-side weights to bf16 hi/lo B-frag layout [n][k].
// ---------------------------------------------------------------------------
__global__ __launch_bounds__(256) void prep_weights(const float* __restrict__ Wlin,
                                                    const float* __restrict__ Wm1,
                                                    const float* __restrict__ Wm2,
                                                    ushort_t* __restrict__ wlhi,
                                                    ushort_t* __restrict__ wllo,
                                                    ushort_t* __restrict__ wm1hi,
                                                    ushort_t* __restrict__ wm1lo,
                                                    ushort_t* __restrict__ wm2hi,
                                                    ushort_t* __restrict__ wm2lo) {
    int idx = blockIdx.x * 256 + threadIdx.x;   // 0..16383
    int n = idx >> 7, k = idx & 127;
    {   float w = Wlin[(size_t)n * CH + k];     // y = x @ W^T  -> B[n][k] = W[n][k]
        ushort_t hi = f2bf(w); wlhi[n * CH + k] = hi; wllo[n * CH + k] = f2bf(w - bf2f(hi)); }
    {   float w = Wm1[(size_t)k * CH + n];      // y = x @ W    -> B[n][k] = W[k][n]
        ushort_t hi = f2bf(w); wm1hi[n * CH + k] = hi; wm1lo[n * CH + k] = f2bf(w - bf2f(hi)); }
    {   float w = Wm2[(size_t)k * CH + n];
        ushort_t hi = f2bf(w); wm2hi[n * CH + k] = hi; wm2lo[n * CH + k] = f2bf(w - bf2f(hi)); }
}

// ---------------------------------------------------------------------------
// ef(r) lookup table: exact fp32 pipeline at 4096 grid points over [0,5].
// ---------------------------------------------------------------------------
__global__ __launch_bounds__(128) void table_build(const float* __restrict__ Wf1,
                                                   const float* __restrict__ bf1,
                                                   const float* __restrict__ Wf2,
                                                   const float* __restrict__ bf2,
                                                   float* __restrict__ tab) {
    __shared__ float bas[64];
    __shared__ float t1[128];
    const int g = blockIdx.x, tid = threadIdx.x;
    const float r = (float)g * (5.0f / (float)(NR - 1));
    if (tid < 64) {
        float v = 0.f;
        if (tid < NF) { float d = r - (float)tid * DELTA; v = __expf(-COEF * d * d); }
        bas[tid] = v;
    }
    __syncthreads();
    float acc = bf1[tid];
    for (int k = 0; k < NF; k++) acc = fmaf(bas[k], Wf1[k * CH + tid], acc);
    t1[tid] = ssp(acc);
    __syncthreads();
    float acc2 = bf2[tid];
    for (int k = 0; k < CH; k++) acc2 = fmaf(t1[k], Wf2[k * CH + tid], acc2);
    tab[(size_t)g * CH + tid] = acc2;
}

// ---------------------------------------------------------------------------
// Counting sort of edges by receiver; scatter emits packed per-edge meta.
// ---------------------------------------------------------------------------
__global__ __launch_bounds__(256) void hist_kernel(const int* __restrict__ recv,
                                                   int* __restrict__ counts) {
    int e = blockIdx.x * 256 + threadIdx.x;
    if (e < N_EDGES) atomicAdd(&counts[recv[e]], 1);
}

__global__ __launch_bounds__(256) void scan1_kernel(const int* __restrict__ counts,
                                                    int* __restrict__ cursor,
                                                    int* __restrict__ bsum) {
    __shared__ int s[256];
    int tid = threadIdx.x;
    int i = blockIdx.x * 256 + tid;
    int v = (i < N_NODES) ? counts[i] : 0;
    s[tid] = v;
    __syncthreads();
    for (int off = 1; off < 256; off <<= 1) {
        int t = (tid >= off) ? s[tid - off] : 0;
        __syncthreads();
        s[tid] += t;
        __syncthreads();
    }
    if (i < N_NODES) cursor[i] = s[tid] - v;
    if (tid == 255) bsum[blockIdx.x] = s[255];
}

__global__ __launch_bounds__(256) void scan2_kernel(int* __restrict__ bsum, int nb) {
    __shared__ int s[256];
    int tid = threadIdx.x;
    int v = (tid < nb) ? bsum[tid] : 0;
    s[tid] = v;
    __syncthreads();
    for (int off = 1; off < 256; off <<= 1) {
        int t = (tid >= off) ? s[tid - off] : 0;
        __syncthreads();
        s[tid] += t;
        __syncthreads();
    }
    if (tid < nb) bsum[tid] = s[tid] - v;
}

__global__ __launch_bounds__(256) void scan3_kernel(int* __restrict__ cursor,
                                                    const int* __restrict__ bsum) {
    int i = blockIdx.x * 256 + threadIdx.x;
    if (i < N_NODES) cursor[i] += bsum[blockIdx.x];
}

__global__ __launch_bounds__(256) void scatter_kernel(const int* __restrict__ recv,
                                                      const int* __restrict__ send,
                                                      const float* __restrict__ dist,
                                                      int* __restrict__ cursor,
                                                      int* __restrict__ msend,
                                                      float* __restrict__ mx) {
    int e = blockIdx.x * 256 + threadIdx.x;
    if (e < N_EDGES) {
        int pos = atomicAdd(&cursor[recv[e]], 1);
        msend[pos] = send[e];
        mx[pos] = fminf(dist[e] * RSCALE, (float)(NR - 1));
    }
}

// ---------------------------------------------------------------------------
// dense_h: h = features @ Wlin^T, output bf16 (halves edge-gather traffic).
// ---------------------------------------------------------------------------
__global__ __launch_bounds__(256) void dense_h(const float* __restrict__ X,
                                               const ushort_t* __restrict__ Bhi,
                                               const ushort_t* __restrict__ Blo,
                                               ushort_t* __restrict__ Y, int M) {
    __shared__ ushort_t xs[64][136];
    const int tid  = threadIdx.x;
    const int row0 = blockIdx.x * 64;

#pragma unroll
    for (int i = 0; i < 8; i++) {
        int idx = tid + i * 256;
        int r   = idx >> 5;
        int c4  = (idx & 31) * 4;
        float4 v = (row0 + r < M) ? *(const float4*)&X[(size_t)(row0 + r) * CH + c4]
                                  : f4zero();
        ushort4 s;
        s.x = f2bf(v.x); s.y = f2bf(v.y); s.z = f2bf(v.z); s.w = f2bf(v.w);
        *(ushort4*)&xs[r][c4] = s;
    }
    __syncthreads();

    const int lane = tid & 63;
    const int wv   = tid >> 6;
    const int row  = lane & 15;
    const int quad = lane >> 4;
    const int c0   = (2 * wv) * 16 + row;
    const int c1   = c0 + 16;

    f32x4 acc[2][4];
#pragma unroll
    for (int j = 0; j < 2; j++)
#pragma unroll
        for (int rt = 0; rt < 4; rt++) acc[j][rt] = (f32x4){0.f, 0.f, 0.f, 0.f};

#pragma unroll
    for (int kb = 0; kb < 128; kb += 32) {
        bf16x8 B0h = *(const bf16x8*)&Bhi[(size_t)c0 * CH + kb + quad * 8];
        bf16x8 B0l = *(const bf16x8*)&Blo[(size_t)c0 * CH + kb + quad * 8];
        bf16x8 B1h = *(const bf16x8*)&Bhi[(size_t)c1 * CH + kb + quad * 8];
        bf16x8 B1l = *(const bf16x8*)&Blo[(size_t)c1 * CH + kb + quad * 8];
#pragma unroll
        for (int rt = 0; rt < 4; rt++) {
            bf16x8 A = *(const bf16x8*)&xs[rt * 16 + row][kb + quad * 8];
            acc[0][rt] = __builtin_amdgcn_mfma_f32_16x16x32_bf16(A, B0l, acc[0][rt], 0, 0, 0);
            acc[0][rt] = __builtin_amdgcn_mfma_f32_16x16x32_bf16(A, B0h, acc[0][rt], 0, 0, 0);
            acc[1][rt] = __builtin_amdgcn_mfma_f32_16x16x32_bf16(A, B1l, acc[1][rt], 0, 0, 0);
            acc[1][rt] = __builtin_amdgcn_mfma_f32_16x16x32_bf16(A, B1h, acc[1][rt], 0, 0, 0);
        }
    }

#pragma unroll
    for (int j = 0; j < 2; j++) {
        int c = j ? c1 : c0;
#pragma unroll
        for (int rt = 0; rt < 4; rt++)
#pragma unroll
            for (int rg = 0; rg < 4; rg++) {
                int r = row0 + rt * 16 + quad * 4 + rg;
                if (r < M) Y[(size_t)r * CH + c] = f2bf(acc[j][rt][rg]);
            }
    }
}

// ---------------------------------------------------------------------------
// Fused output MLP: out = ssp(agg @ Wm1 + bm1) @ Wm2 + bm2, in-place on agg.
// ---------------------------------------------------------------------------
__global__ __launch_bounds__(256) void out_mlp(const float* __restrict__ AGG,
                                               const ushort_t* __restrict__ B1hi,
                                               const ushort_t* __restrict__ B1lo,
                                               const float* __restrict__ bm1,
                                               const ushort_t* __restrict__ B2hi,
                                               const ushort_t* __restrict__ B2lo,
                                               const float* __restrict__ bm2,
                                               float* __restrict__ OUT, int M) {
    __shared__ ushort_t xs[64][136];
    __shared__ ushort_t ts[64][136];
    const int tid  = threadIdx.x;
    const int row0 = blockIdx.x * 64;

#pragma unroll
    for (int i = 0; i < 8; i++) {
        int idx = tid + i * 256;
        int r   = idx >> 5;
        int c4  = (idx & 31) * 4;
        float4 v = (row0 + r < M) ? *(const float4*)&AGG[(size_t)(row0 + r) * CH + c4]
                                  : f4zero();
        ushort4 s;
        s.x = f2bf(v.x); s.y = f2bf(v.y); s.z = f2bf(v.z); s.w = f2bf(v.w);
        *(ushort4*)&xs[r][c4] = s;
    }
    __syncthreads();

    const int lane = tid & 63;
    const int wv   = tid >> 6;
    const int row  = lane & 15;
    const int quad = lane >> 4;
    const int c0   = (2 * wv) * 16 + row;
    const int c1   = c0 + 16;

    f32x4 acc[2][4];
#pragma unroll
    for (int j = 0; j < 2; j++)
#pragma unroll
        for (int rt = 0; rt < 4; rt++) acc[j][rt] = (f32x4){0.f, 0.f, 0.f, 0.f};

    // GEMM-A: t = ssp(agg @ Wm1 + bm1)
#pragma unroll
    for (int kb = 0; kb < 128; kb += 32) {
        bf16x8 B0h = *(const bf16x8*)&B1hi[(size_t)c0 * CH + kb + quad * 8];
        bf16x8 B0l = *(const bf16x8*)&B1lo[(size_t)c0 * CH + kb + quad * 8];
        bf16x8 B1h_ = *(const bf16x8*)&B1hi[(size_t)c1 * CH + kb + quad * 8];
        bf16x8 B1l_ = *(const bf16x8*)&B1lo[(size_t)c1 * CH + kb + quad * 8];
#pragma unroll
        for (int rt = 0; rt < 4; rt++) {
            bf16x8 A = *(const bf16x8*)&xs[rt * 16 + row][kb + quad * 8];
            acc[0][rt] = __builtin_amdgcn_mfma_f32_16x16x32_bf16(A, B0l, acc[0][rt], 0, 0, 0);
            acc[0][rt] = __builtin_amdgcn_mfma_f32_16x16x32_bf16(A, B0h, acc[0][rt], 0, 0, 0);
            acc[1][rt] = __builtin_amdgcn_mfma_f32_16x16x32_bf16(A, B1l_, acc[1][rt], 0, 0, 0);
            acc[1][rt] = __builtin_amdgcn_mfma_f32_16x16x32_bf16(A, B1h_, acc[1][rt], 0, 0, 0);
        }
    }
    {
        float bv[2] = { bm1[c0], bm1[c1] };
#pragma unroll
        for (int j = 0; j < 2; j++) {
            int c = j ? c1 : c0;
#pragma unroll
            for (int rt = 0; rt < 4; rt++)
#pragma unroll
                for (int rg = 0; rg < 4; rg++)
                    ts[rt * 16 + quad * 4 + rg][c] = f2bf(ssp(acc[j][rt][rg] + bv[j]));
        }
    }
    __syncthreads();

    // GEMM-B: out = t @ Wm2 + bm2
#pragma unroll
    for (int j = 0; j < 2; j++)
#pragma unroll
        for (int rt = 0; rt < 4; rt++) acc[j][rt] = (f32x4){0.f, 0.f, 0.f, 0.f};

#pragma unroll
    for (int kb = 0; kb < 128; kb += 32) {
        bf16x8 B0h = *(const bf16x8*)&B2hi[(size_t)c0 * CH + kb + quad * 8];
        bf16x8 B0l = *(const bf16x8*)&B2lo[(size_t)c0 * CH + kb + quad * 8];
        bf16x8 B1h_ = *(const bf16x8*)&B2hi[(size_t)c1 * CH + kb + quad * 8];
        bf16x8 B1l_ = *(const bf16x8*)&B2lo[(size_t)c1 * CH + kb + quad * 8];
#pragma unroll
        for (int rt = 0; rt < 4; rt++) {
            bf16x8 A = *(const bf16x8*)&ts[rt * 16 + row][kb + quad * 8];
            acc[0][rt] = __builtin_amdgcn_mfma_f32_16x16x32_bf16(A, B0l, acc[0][rt], 0, 0, 0);
            acc[0][rt] = __builtin_amdgcn_mfma_f32_16x16x32_bf16(A, B0h, acc[0][rt], 0, 0, 0);
            acc[1][rt] = __builtin_amdgcn_mfma_f32_16x16x32_bf16(A, B1l_, acc[1][rt], 0, 0, 0);
            acc[1][rt] = __builtin_amdgcn_mfma_f32_16x16x32_bf16(A, B1h_, acc[1][rt], 0, 0, 0);
        }
    }
    {
        float bv[2] = { bm2[c0], bm2[c1] };
#pragma unroll
        for (int j = 0; j < 2; j++) {
            int c = j ? c1 : c0;
#pragma unroll
            for (int rt = 0; rt < 4; rt++)
#pragma unroll
                for (int rg = 0; rg < 4; rg++) {
                    int r = row0 + rt * 16 + quad * 4 + rg;
                    if (r < M) OUT[(size_t)r * CH + c] = acc[j][rt][rg] + bv[j];
                }
        }
    }
}

// ---------------------------------------------------------------------------
// Edge gather: block owns 8 consecutive nodes (receiver-sorted edge ranges
// are contiguous). 32-thread group per node, float4 channel quad per thread.
// ef via table lerp; register accumulation; plain stores. No atomics.
// ---------------------------------------------------------------------------
__global__ __launch_bounds__(256) void edge_gather(const int* __restrict__ cursor,
                                                   const int* __restrict__ msend,
                                                   const float* __restrict__ mx,
                                                   const ushort_t* __restrict__ h,
                                                   const float* __restrict__ tab,
                                                   float* __restrict__ agg) {
    __shared__ int   ssend[CHUNK];
    __shared__ float sx[CHUNK];

    const int tid = threadIdx.x;
    const int n0  = blockIdx.x * NODES_PER_BLK;
    const int g   = tid >> 5;              // group 0..7 -> node n0+g
    const int c4  = (tid & 31) * 4;
    const int n   = n0 + g;

    const int myend  = cursor[n];
    const int mybeg  = (n == 0) ? 0 : cursor[n - 1];
    const int blkbeg = (n0 == 0) ? 0 : cursor[n0 - 1];
    const int blkend = cursor[n0 + NODES_PER_BLK - 1];

    float4 macc = f4zero();

    for (int cs = blkbeg; cs < blkend; cs += CHUNK) {
        const int ce = min(cs + CHUNK, blkend);
        __syncthreads();
        for (int i = tid; i < ce - cs; i += 256) {
            ssend[i] = msend[cs + i];
            sx[i]    = mx[cs + i];
        }
        __syncthreads();

        const int lo = max(mybeg, cs), hi = min(myend, ce);
        for (int e = lo; e < hi; e++) {
            int   s  = ssend[e - cs];
            float x  = sx[e - cs];
            float fx = floorf(x);
            int   ti = min((int)fx, NR - 2);
            float fr = x - fx;

            ushort4 hu = *(const ushort4*)&h[(size_t)s * CH + c4];
            float4  ta = *(const float4*)&tab[(size_t)ti * CH + c4];
            float4  tb = *(const float4*)&tab[(size_t)(ti + 1) * CH + c4];

            float4 ef;
            ef.x = fmaf(fr, tb.x - ta.x, ta.x);
            ef.y = fmaf(fr, tb.y - ta.y, ta.y);
            ef.z = fmaf(fr, tb.z - ta.z, ta.z);
            ef.w = fmaf(fr, tb.w - ta.w, ta.w);

            macc.x = fmaf(bf2f(hu.x), ef.x, macc.x);
            macc.y = fmaf(bf2f(hu.y), ef.y, macc.y);
            macc.z = fmaf(bf2f(hu.z), ef.z, macc.z);
            macc.w = fmaf(bf2f(hu.w), ef.w, macc.w);
        }
    }

    *(float4*)&agg[(size_t)n * CH + c4] = macc;
}

// ---------------------------------------------------------------------------
extern "C" void kernel_launch(void* const* d_in, const int* in_sizes, int n_in,
                              void* d_out, int out_size, void* d_ws, size_t ws_size,
                              hipStream_t stream) {
    const float* features = (const float*)d_in[0];
    const float* dist     = (const float*)d_in[1];
    const float* W_lin    = (const float*)d_in[2];
    const float* Wf1      = (const float*)d_in[3];
    const float* bf1      = (const float*)d_in[4];
    const float* Wf2      = (const float*)d_in[5];
    const float* bf2      = (const float*)d_in[6];
    const float* Wm1      = (const float*)d_in[7];
    const float* bm1      = (const float*)d_in[8];
    const float* Wm2      = (const float*)d_in[9];
    const float* bm2      = (const float*)d_in[10];
    const int* senders    = (const int*)d_in[11];
    const int* receivers  = (const int*)d_in[12];
    float* out = (float*)d_out;

    // workspace (~28.5 MB)
    ushort_t* h     = (ushort_t*)d_ws;                     // [N,128] bf16
    int*   msend    = (int*)(h + (size_t)N_NODES * CH);    // [E]
    float* mx       = (float*)(msend + N_EDGES);           // [E]
    int*   counts   = (int*)(mx + N_EDGES);                // [N]
    int*   cursor   = counts + N_NODES;                    // [N]
    int*   bsum     = cursor + N_NODES;                    // [256]
    float* tab      = (float*)(bsum + 256);                // [NR,128]
    ushort_t* wlhi  = (ushort_t*)(tab + (size_t)NR * CH);
    ushort_t* wllo  = wlhi  + CH * CH;
    ushort_t* wm1hi = wllo  + CH * CH;
    ushort_t* wm1lo = wm1hi + CH * CH;
    ushort_t* wm2hi = wm1lo + CH * CH;
    ushort_t* wm2lo = wm2hi + CH * CH;

    hipMemsetAsync(counts, 0, (size_t)N_NODES * sizeof(int), stream);

    prep_weights<<<64, 256, 0, stream>>>(W_lin, Wm1, Wm2,
                                         wlhi, wllo, wm1hi, wm1lo, wm2hi, wm2lo);
    table_build<<<NR, 128, 0, stream>>>(Wf1, bf1, Wf2, bf2, tab);

    const int nb_scan = (N_NODES + 255) / 256;   // 196
    hist_kernel<<<(N_EDGES + 255) / 256, 256, 0, stream>>>(receivers, counts);
    scan1_kernel<<<nb_scan, 256, 0, stream>>>(counts, cursor, bsum);
    scan2_kernel<<<1, 256, 0, stream>>>(bsum, nb_scan);
    scan3_kernel<<<nb_scan, 256, 0, stream>>>(cursor, bsum);
    scatter_kernel<<<(N_EDGES + 255) / 256, 256, 0, stream>>>(receivers, senders, dist,
                                                              cursor, msend, mx);

    const int nb_dense = (N_NODES + 63) / 64;    // 782
    dense_h<<<nb_dense, 256, 0, stream>>>(features, wlhi, wllo, h, N_NODES);

    // gather/aggregate into d_out (no atomics, no memset needed — every row stored)
    edge_gather<<<N_NODES / NODES_PER_BLK, 256, 0, stream>>>(cursor, msend, mx, h, tab, out);

    // fused output MLP, in-place on d_out
    out_mlp<<<nb_dense, 256, 0, stream>>>(out, wm1hi, wm1lo, bm1, wm2hi, wm2lo, bm2, out, N_NODES);
}

// Round 6
// 337.407 us; speedup vs baseline: 9.4229x; 1.3871x over previous
//
#include <hip/hip_runtime.h>
#include <hip/hip_bf16.h>
#include <math.h>

#define N_NODES 50000
#define N_EDGES 1600000
#define CH 128
#define NF 50
#define NR 4096            // ef(r) table resolution
#define NODES_PER_BLK 8
#define CHUNK 1024
#define NB 512             // sort buckets
#define BUCKET_NODES 98    // 512*98 = 50176 >= N_NODES
#define PASSA_CHUNK 4096   // edges per pass-A block (16/thread)
#define PASSB_CAP 4608     // LDS capacity per bucket (mean 3136, sd 56 -> +26 sigma)

constexpr float DELTA  = 5.0f / 49.0f;             // linspace(0,5,50) spacing
constexpr float COEF   = 1.0f / (2.0f * DELTA * DELTA);
constexpr float LOG2_  = 0.6931471805599453f;
constexpr float RSCALE = (float)(NR - 1) / 5.0f;   // r -> grid coordinate

typedef short  bf16x8 __attribute__((ext_vector_type(8)));
typedef float  f32x4  __attribute__((ext_vector_type(4)));
typedef unsigned short ushort_t;
typedef unsigned long long u64;

__device__ __forceinline__ float ssp(float x) {
    return fmaxf(x, 0.0f) + __logf(1.0f + __expf(-fabsf(x))) - LOG2_;
}
__device__ __forceinline__ ushort_t f2bf(float x) {
    __hip_bfloat16 b = __float2bfloat16(x);
    return *reinterpret_cast<ushort_t*>(&b);
}
__device__ __forceinline__ float bf2f(ushort_t u) {
    return __uint_as_float(((unsigned)u) << 16);
}
__device__ __forceinline__ float4 f4zero() { return make_float4(0.f, 0.f, 0.f, 0.f); }

// ---------------------------------------------------------------------------
// Weight prep: node-side weights to bf16 hi/lo B-frag layout [n][k].
// ---------------------------------------------------------------------------
__global__ __launch_bounds__(256) void prep_weights(const float* __restrict__ Wlin,
                                                    const float* __restrict__ Wm1,
                                                    const float* __restrict__ Wm2,
                                                    ushort_t* __restrict__ wlhi,
                                                    ushort_t* __restrict__ wllo,
                                                    ushort_t* __restrict__ wm1hi,
                                                    ushort_t* __restrict__ wm1lo,
                                                    ushort_t* __restrict__ wm2hi,
                                                    ushort_t* __restrict__ wm2lo) {
    int idx = blockIdx.x * 256 + threadIdx.x;   // 0..16383
    int n = idx >> 7, k = idx & 127;
    {   float w = Wlin[(size_t)n * CH + k];     // y = x @ W^T  -> B[n][k] = W[n][k]
        ushort_t hi = f2bf(w); wlhi[n * CH + k] = hi; wllo[n * CH + k] = f2bf(w - bf2f(hi)); }
    {   float w = Wm1[(size_t)k * CH + n];      // y = x @ W    -> B[n][k] = W[k][n]
        ushort_t hi = f2bf(w); wm1hi[n * CH + k] = hi; wm1lo[n * CH + k] = f2bf(w - bf2f(hi)); }
    {   float w = Wm2[(size_t)k * CH + n];
        ushort_t hi = f2bf(w); wm2hi[n * CH + k] = hi; wm2lo[n * CH + k] = f2bf(w - bf2f(hi)); }
}

// ---------------------------------------------------------------------------
// ef(r) lookup table: exact fp32 pipeline at 4096 grid points over [0,5].
// ---------------------------------------------------------------------------
__global__ __launch_bounds__(128) void table_build(const float* __restrict__ Wf1,
                                                   const float* __restrict__ bf1,
                                                   const float* __restrict__ Wf2,
                                                   const float* __restrict__ bf2,
                                                   float* __restrict__ tab) {
    __shared__ float bas[64];
    __shared__ float t1[128];
    const int g = blockIdx.x, tid = threadIdx.x;
    const float r = (float)g * (5.0f / (float)(NR - 1));
    if (tid < 64) {
        float v = 0.f;
        if (tid < NF) { float d = r - (float)tid * DELTA; v = __expf(-COEF * d * d); }
        bas[tid] = v;
    }
    __syncthreads();
    float acc = bf1[tid];
    for (int k = 0; k < NF; k++) acc = fmaf(bas[k], Wf1[k * CH + tid], acc);
    t1[tid] = ssp(acc);
    __syncthreads();
    float acc2 = bf2[tid];
    for (int k = 0; k < CH; k++) acc2 = fmaf(t1[k], Wf2[k * CH + tid], acc2);
    tab[(size_t)g * CH + tid] = acc2;
}

// ---------------------------------------------------------------------------
// Two-pass bucket sort of edges by receiver.
// Record: send(16b) | recv(16b) | x_bits(32b)  — both IDs < 65536.
// ---------------------------------------------------------------------------
__global__ __launch_bounds__(256) void bucket_hist(const int* __restrict__ recv,
                                                   int* __restrict__ bcnt) {
    __shared__ int bh[NB];
    const int tid = threadIdx.x;
    for (int i = tid; i < NB; i += 256) bh[i] = 0;
    __syncthreads();
    const int e0 = blockIdx.x * PASSA_CHUNK;
#pragma unroll
    for (int i = 0; i < 16; i++) {
        int e = e0 + tid + i * 256;
        if (e < N_EDGES) atomicAdd(&bh[recv[e] / BUCKET_NODES], 1);
    }
    __syncthreads();
    for (int i = tid; i < NB; i += 256)
        if (bh[i]) atomicAdd(&bcnt[i], bh[i]);
}

__global__ __launch_bounds__(256) void bucket_scan(const int* __restrict__ bcnt,
                                                   int* __restrict__ bbase,
                                                   int* __restrict__ bcursor) {
    __shared__ int s[NB];
    const int tid = threadIdx.x;
    s[tid] = bcnt[tid];
    s[tid + 256] = bcnt[tid + 256];
    __syncthreads();
    if (tid == 0) {
        int acc = 0;
        for (int i = 0; i < NB; i++) { int c = s[i]; s[i] = acc; acc += c; }
    }
    __syncthreads();
    bbase[tid] = s[tid];           bbase[tid + 256] = s[tid + 256];
    bcursor[tid] = s[tid];         bcursor[tid + 256] = s[tid + 256];
    if (tid == 0) bbase[NB] = N_EDGES;
}

__global__ __launch_bounds__(256) void bucket_scatter(const int* __restrict__ recv,
                                                      const int* __restrict__ send,
                                                      const float* __restrict__ dist,
                                                      int* __restrict__ bcursor,
                                                      u64* __restrict__ brec) {
    __shared__ int bbaseL[NB];
    __shared__ int bcur[NB];
    const int tid = threadIdx.x;
    for (int i = tid; i < NB; i += 256) bcur[i] = 0;
    __syncthreads();
    const int e0 = blockIdx.x * PASSA_CHUNK;
#pragma unroll
    for (int i = 0; i < 16; i++) {
        int e = e0 + tid + i * 256;
        if (e < N_EDGES) atomicAdd(&bcur[recv[e] / BUCKET_NODES], 1);
    }
    __syncthreads();
    for (int i = tid; i < NB; i += 256) {
        int c = bcur[i];
        if (c) bbaseL[i] = atomicAdd(&bcursor[i], c);
        bcur[i] = 0;
    }
    __syncthreads();
#pragma unroll
    for (int i = 0; i < 16; i++) {
        int e = e0 + tid + i * 256;
        if (e < N_EDGES) {
            int r = recv[e];
            int b = r / BUCKET_NODES;
            int rank = atomicAdd(&bcur[b], 1);
            float x = fminf(dist[e] * RSCALE, (float)(NR - 1));
            u64 rec = (u64)(unsigned)(send[e] | (r << 16)) |
                      ((u64)__float_as_uint(x) << 32);
            brec[bbaseL[b] + rank] = rec;
        }
    }
}

// One workgroup per bucket: node-sort its ~3.1K edges entirely in LDS,
// stream out coalesced; also emit per-node inclusive-end cursor.
__global__ __launch_bounds__(256) void bucket_sort(const int* __restrict__ bbase,
                                                   const u64* __restrict__ brec,
                                                   u64* __restrict__ meta,
                                                   int* __restrict__ cursor) {
    __shared__ int shist[BUCKET_NODES];
    __shared__ int sexc[BUCKET_NODES];
    __shared__ u64 sout[PASSB_CAP];
    const int b = blockIdx.x, tid = threadIdx.x;
    const int nbase = b * BUCKET_NODES;
    const int nn = min(BUCKET_NODES, N_NODES - nbase);
    if (nn <= 0) return;
    const int ebase = bbase[b], m = bbase[b + 1] - ebase;

    for (int i = tid; i < nn; i += 256) shist[i] = 0;
    __syncthreads();
    for (int i = tid; i < m; i += 256) {
        int l = (int)((brec[ebase + i] >> 16) & 0xFFFF) - nbase;
        atomicAdd(&shist[l], 1);
    }
    __syncthreads();
    if (tid == 0) {
        int acc = 0;
        for (int l = 0; l < nn; l++) { sexc[l] = acc; acc += shist[l]; }
    }
    __syncthreads();
    for (int l = tid; l < nn; l += 256)
        cursor[nbase + l] = ebase + sexc[l] + shist[l];
    __syncthreads();
    for (int i = tid; i < m; i += 256) {
        u64 rec = brec[ebase + i];
        int l = (int)((rec >> 16) & 0xFFFF) - nbase;
        int rank = atomicAdd(&sexc[l], 1);
        if (rank < PASSB_CAP) sout[rank] = rec;
    }
    __syncthreads();
    for (int i = tid; i < m; i += 256) meta[ebase + i] = sout[i];
}

// ---------------------------------------------------------------------------
// dense_h: h = features @ Wlin^T, output bf16 (halves edge-gather traffic).
// ---------------------------------------------------------------------------
__global__ __launch_bounds__(256) void dense_h(const float* __restrict__ X,
                                               const ushort_t* __restrict__ Bhi,
                                               const ushort_t* __restrict__ Blo,
                                               ushort_t* __restrict__ Y, int M) {
    __shared__ ushort_t xs[64][136];
    const int tid  = threadIdx.x;
    const int row0 = blockIdx.x * 64;

#pragma unroll
    for (int i = 0; i < 8; i++) {
        int idx = tid + i * 256;
        int r   = idx >> 5;
        int c4  = (idx & 31) * 4;
        float4 v = (row0 + r < M) ? *(const float4*)&X[(size_t)(row0 + r) * CH + c4]
                                  : f4zero();
        ushort4 s;
        s.x = f2bf(v.x); s.y = f2bf(v.y); s.z = f2bf(v.z); s.w = f2bf(v.w);
        *(ushort4*)&xs[r][c4] = s;
    }
    __syncthreads();

    const int lane = tid & 63;
    const int wv   = tid >> 6;
    const int row  = lane & 15;
    const int quad = lane >> 4;
    const int c0   = (2 * wv) * 16 + row;
    const int c1   = c0 + 16;

    f32x4 acc[2][4];
#pragma unroll
    for (int j = 0; j < 2; j++)
#pragma unroll
        for (int rt = 0; rt < 4; rt++) acc[j][rt] = (f32x4){0.f, 0.f, 0.f, 0.f};

#pragma unroll
    for (int kb = 0; kb < 128; kb += 32) {
        bf16x8 B0h = *(const bf16x8*)&Bhi[(size_t)c0 * CH + kb + quad * 8];
        bf16x8 B0l = *(const bf16x8*)&Blo[(size_t)c0 * CH + kb + quad * 8];
        bf16x8 B1h = *(const bf16x8*)&Bhi[(size_t)c1 * CH + kb + quad * 8];
        bf16x8 B1l = *(const bf16x8*)&Blo[(size_t)c1 * CH + kb + quad * 8];
#pragma unroll
        for (int rt = 0; rt < 4; rt++) {
            bf16x8 A = *(const bf16x8*)&xs[rt * 16 + row][kb + quad * 8];
            acc[0][rt] = __builtin_amdgcn_mfma_f32_16x16x32_bf16(A, B0l, acc[0][rt], 0, 0, 0);
            acc[0][rt] = __builtin_amdgcn_mfma_f32_16x16x32_bf16(A, B0h, acc[0][rt], 0, 0, 0);
            acc[1][rt] = __builtin_amdgcn_mfma_f32_16x16x32_bf16(A, B1l, acc[1][rt], 0, 0, 0);
            acc[1][rt] = __builtin_amdgcn_mfma_f32_16x16x32_bf16(A, B1h, acc[1][rt], 0, 0, 0);
        }
    }

#pragma unroll
    for (int j = 0; j < 2; j++) {
        int c = j ? c1 : c0;
#pragma unroll
        for (int rt = 0; rt < 4; rt++)
#pragma unroll
            for (int rg = 0; rg < 4; rg++) {
                int r = row0 + rt * 16 + quad * 4 + rg;
                if (r < M) Y[(size_t)r * CH + c] = f2bf(acc[j][rt][rg]);
            }
    }
}

// ---------------------------------------------------------------------------
// Fused output MLP: out = ssp(agg @ Wm1 + bm1) @ Wm2 + bm2, in-place on agg.
// ---------------------------------------------------------------------------
__global__ __launch_bounds__(256) void out_mlp(const float* __restrict__ AGG,
                                               const ushort_t* __restrict__ B1hi,
                                               const ushort_t* __restrict__ B1lo,
                                               const float* __restrict__ bm1,
                                               const ushort_t* __restrict__ B2hi,
                                               const ushort_t* __restrict__ B2lo,
                                               const float* __restrict__ bm2,
                                               float* __restrict__ OUT, int M) {
    __shared__ ushort_t xs[64][136];
    __shared__ ushort_t ts[64][136];
    const int tid  = threadIdx.x;
    const int row0 = blockIdx.x * 64;

#pragma unroll
    for (int i = 0; i < 8; i++) {
        int idx = tid + i * 256;
        int r   = idx >> 5;
        int c4  = (idx & 31) * 4;
        float4 v = (row0 + r < M) ? *(const float4*)&AGG[(size_t)(row0 + r) * CH + c4]
                                  : f4zero();
        ushort4 s;
        s.x = f2bf(v.x); s.y = f2bf(v.y); s.z = f2bf(v.z); s.w = f2bf(v.w);
        *(ushort4*)&xs[r][c4] = s;
    }
    __syncthreads();

    const int lane = tid & 63;
    const int wv   = tid >> 6;
    const int row  = lane & 15;
    const int quad = lane >> 4;
    const int c0   = (2 * wv) * 16 + row;
    const int c1   = c0 + 16;

    f32x4 acc[2][4];
#pragma unroll
    for (int j = 0; j < 2; j++)
#pragma unroll
        for (int rt = 0; rt < 4; rt++) acc[j][rt] = (f32x4){0.f, 0.f, 0.f, 0.f};

    // GEMM-A: t = ssp(agg @ Wm1 + bm1)
#pragma unroll
    for (int kb = 0; kb < 128; kb += 32) {
        bf16x8 B0h = *(const bf16x8*)&B1hi[(size_t)c0 * CH + kb + quad * 8];
        bf16x8 B0l = *(const bf16x8*)&B1lo[(size_t)c0 * CH + kb + quad * 8];
        bf16x8 B1h_ = *(const bf16x8*)&B1hi[(size_t)c1 * CH + kb + quad * 8];
        bf16x8 B1l_ = *(const bf16x8*)&B1lo[(size_t)c1 * CH + kb + quad * 8];
#pragma unroll
        for (int rt = 0; rt < 4; rt++) {
            bf16x8 A = *(const bf16x8*)&xs[rt * 16 + row][kb + quad * 8];
            acc[0][rt] = __builtin_amdgcn_mfma_f32_16x16x32_bf16(A, B0l, acc[0][rt], 0, 0, 0);
            acc[0][rt] = __builtin_amdgcn_mfma_f32_16x16x32_bf16(A, B0h, acc[0][rt], 0, 0, 0);
            acc[1][rt] = __builtin_amdgcn_mfma_f32_16x16x32_bf16(A, B1l_, acc[1][rt], 0, 0, 0);
            acc[1][rt] = __builtin_amdgcn_mfma_f32_16x16x32_bf16(A, B1h_, acc[1][rt], 0, 0, 0);
        }
    }
    {
        float bv[2] = { bm1[c0], bm1[c1] };
#pragma unroll
        for (int j = 0; j < 2; j++) {
            int c = j ? c1 : c0;
#pragma unroll
            for (int rt = 0; rt < 4; rt++)
#pragma unroll
                for (int rg = 0; rg < 4; rg++)
                    ts[rt * 16 + quad * 4 + rg][c] = f2bf(ssp(acc[j][rt][rg] + bv[j]));
        }
    }
    __syncthreads();

    // GEMM-B: out = t @ Wm2 + bm2
#pragma unroll
    for (int j = 0; j < 2; j++)
#pragma unroll
        for (int rt = 0; rt < 4; rt++) acc[j][rt] = (f32x4){0.f, 0.f, 0.f, 0.f};

#pragma unroll
    for (int kb = 0; kb < 128; kb += 32) {
        bf16x8 B0h = *(const bf16x8*)&B2hi[(size_t)c0 * CH + kb + quad * 8];
        bf16x8 B0l = *(const bf16x8*)&B2lo[(size_t)c0 * CH + kb + quad * 8];
        bf16x8 B1h_ = *(const bf16x8*)&B2hi[(size_t)c1 * CH + kb + quad * 8];
        bf16x8 B1l_ = *(const bf16x8*)&B2lo[(size_t)c1 * CH + kb + quad * 8];
#pragma unroll
        for (int rt = 0; rt < 4; rt++) {
            bf16x8 A = *(const bf16x8*)&ts[rt * 16 + row][kb + quad * 8];
            acc[0][rt] = __builtin_amdgcn_mfma_f32_16x16x32_bf16(A, B0l, acc[0][rt], 0, 0, 0);
            acc[0][rt] = __builtin_amdgcn_mfma_f32_16x16x32_bf16(A, B0h, acc[0][rt], 0, 0, 0);
            acc[1][rt] = __builtin_amdgcn_mfma_f32_16x16x32_bf16(A, B1l_, acc[1][rt], 0, 0, 0);
            acc[1][rt] = __builtin_amdgcn_mfma_f32_16x16x32_bf16(A, B1h_, acc[1][rt], 0, 0, 0);
        }
    }
    {
        float bv[2] = { bm2[c0], bm2[c1] };
#pragma unroll
        for (int j = 0; j < 2; j++) {
            int c = j ? c1 : c0;
#pragma unroll
            for (int rt = 0; rt < 4; rt++)
#pragma unroll
                for (int rg = 0; rg < 4; rg++) {
                    int r = row0 + rt * 16 + quad * 4 + rg;
                    if (r < M) OUT[(size_t)r * CH + c] = acc[j][rt][rg] + bv[j];
                }
        }
    }
}

// ---------------------------------------------------------------------------
// Edge gather: block owns 8 consecutive nodes. 32-thread group per node,
// float4 channel quad per thread. ef via table lerp; register accumulation.
// ---------------------------------------------------------------------------
__global__ __launch_bounds__(256) void edge_gather(const int* __restrict__ cursor,
                                                   const u64* __restrict__ meta,
                                                   const ushort_t* __restrict__ h,
                                                   const float* __restrict__ tab,
                                                   float* __restrict__ agg) {
    __shared__ u64 smeta[CHUNK];

    const int tid = threadIdx.x;
    const int n0  = blockIdx.x * NODES_PER_BLK;
    const int g   = tid >> 5;              // group 0..7 -> node n0+g
    const int c4  = (tid & 31) * 4;
    const int n   = n0 + g;

    const int myend  = cursor[n];
    const int mybeg  = (n == 0) ? 0 : cursor[n - 1];
    const int blkbeg = (n0 == 0) ? 0 : cursor[n0 - 1];
    const int blkend = cursor[n0 + NODES_PER_BLK - 1];

    float4 macc = f4zero();

    for (int cs = blkbeg; cs < blkend; cs += CHUNK) {
        const int ce = min(cs + CHUNK, blkend);
        __syncthreads();
        for (int i = tid; i < ce - cs; i += 256) smeta[i] = meta[cs + i];
        __syncthreads();

        const int lo = max(mybeg, cs), hi = min(myend, ce);
        for (int e = lo; e < hi; e++) {
            u64   v  = smeta[e - cs];
            int   s  = (int)(v & 0xFFFF);
            float x  = __uint_as_float((unsigned)(v >> 32));
            float fx = floorf(x);
            int   ti = min((int)fx, NR - 2);
            float fr = x - fx;

            ushort4 hu = *(const ushort4*)&h[(size_t)s * CH + c4];
            float4  ta = *(const float4*)&tab[(size_t)ti * CH + c4];
            float4  tb = *(const float4*)&tab[(size_t)(ti + 1) * CH + c4];

            float4 ef;
            ef.x = fmaf(fr, tb.x - ta.x, ta.x);
            ef.y = fmaf(fr, tb.y - ta.y, ta.y);
            ef.z = fmaf(fr, tb.z - ta.z, ta.z);
            ef.w = fmaf(fr, tb.w - ta.w, ta.w);

            macc.x = fmaf(bf2f(hu.x), ef.x, macc.x);
            macc.y = fmaf(bf2f(hu.y), ef.y, macc.y);
            macc.z = fmaf(bf2f(hu.z), ef.z, macc.z);
            macc.w = fmaf(bf2f(hu.w), ef.w, macc.w);
        }
    }

    *(float4*)&agg[(size_t)n * CH + c4] = macc;
}

// ---------------------------------------------------------------------------
extern "C" void kernel_launch(void* const* d_in, const int* in_sizes, int n_in,
                              void* d_out, int out_size, void* d_ws, size_t ws_size,
                              hipStream_t stream) {
    const float* features = (const float*)d_in[0];
    const float* dist     = (const float*)d_in[1];
    const float* W_lin    = (const float*)d_in[2];
    const float* Wf1      = (const float*)d_in[3];
    const float* bf1      = (const float*)d_in[4];
    const float* Wf2      = (const float*)d_in[5];
    const float* bf2      = (const float*)d_in[6];
    const float* Wm1      = (const float*)d_in[7];
    const float* bm1      = (const float*)d_in[8];
    const float* Wm2      = (const float*)d_in[9];
    const float* bm2      = (const float*)d_in[10];
    const int* senders    = (const int*)d_in[11];
    const int* receivers  = (const int*)d_in[12];
    float* out = (float*)d_out;

    // workspace (~28 MB). brec (12.8 MB) is dead after bucket_sort and is
    // reused as h (bf16 [N,128] = exactly 12.8 MB) — dense_h runs after.
    u64* brec       = (u64*)d_ws;                          // [E] 8B recs
    ushort_t* h     = (ushort_t*)d_ws;                     // alias of brec
    u64* meta       = brec + N_EDGES;                      // [E] sorted recs
    float* tab      = (float*)(meta + N_EDGES);            // [NR,128]
    int* cursor     = (int*)(tab + (size_t)NR * CH);       // [N]
    int* bcnt       = cursor + N_NODES;                    // [NB]
    int* bbase      = bcnt + NB;                           // [NB+1]
    int* bcursor    = bbase + NB + 1;                      // [NB]
    ushort_t* wlhi  = (ushort_t*)(bcursor + NB);
    ushort_t* wllo  = wlhi  + CH * CH;
    ushort_t* wm1hi = wllo  + CH * CH;
    ushort_t* wm1lo = wm1hi + CH * CH;
    ushort_t* wm2hi = wm1lo + CH * CH;
    ushort_t* wm2lo = wm2hi + CH * CH;

    hipMemsetAsync(bcnt, 0, NB * sizeof(int), stream);

    prep_weights<<<64, 256, 0, stream>>>(W_lin, Wm1, Wm2,
                                         wlhi, wllo, wm1hi, wm1lo, wm2hi, wm2lo);
    table_build<<<NR, 128, 0, stream>>>(Wf1, bf1, Wf2, bf2, tab);

    const int nbA = (N_EDGES + PASSA_CHUNK - 1) / PASSA_CHUNK;   // 391
    bucket_hist<<<nbA, 256, 0, stream>>>(receivers, bcnt);
    bucket_scan<<<1, 256, 0, stream>>>(bcnt, bbase, bcursor);
    bucket_scatter<<<nbA, 256, 0, stream>>>(receivers, senders, dist, bcursor, brec);
    bucket_sort<<<NB, 256, 0, stream>>>(bbase, brec, meta, cursor);

    const int nb_dense = (N_NODES + 63) / 64;    // 782
    dense_h<<<nb_dense, 256, 0, stream>>>(features, wlhi, wllo, h, N_NODES);

    // gather/aggregate into d_out (no atomics; every row stored)
    edge_gather<<<N_NODES / NODES_PER_BLK, 256, 0, stream>>>(cursor, meta, h, tab, out);

    // fused output MLP, in-place on d_out
    out_mlp<<<nb_dense, 256, 0, stream>>>(out, wm1hi, wm1lo, bm1, wm2hi, wm2lo, bm2, out, N_NODES);
}

// Round 7
// 289.063 us; speedup vs baseline: 10.9989x; 1.1672x over previous
//
#include <hip/hip_runtime.h>
#include <hip/hip_bf16.h>
#include <math.h>

#define N_NODES 50000
#define N_EDGES 1600000
#define CH 128
#define NF 50
#define NR 4096            // ef(r) table resolution
#define NODES_PER_BLK 8
#define CHUNK 1024
#define NB 512             // sort buckets
#define BUCKET_NODES 98    // 512*98 = 50176 >= N_NODES
#define PASSA_CHUNK 4096   // edges per pass-A block (16/thread)
#define PASSB_CAP 4608     // LDS capacity per bucket

constexpr float DELTA  = 5.0f / 49.0f;             // linspace(0,5,50) spacing
constexpr float COEF   = 1.0f / (2.0f * DELTA * DELTA);
constexpr float LOG2_  = 0.6931471805599453f;
constexpr float RSCALE = (float)(NR - 1) / 5.0f;   // r -> grid coordinate

typedef short  bf16x8 __attribute__((ext_vector_type(8)));
typedef float  f32x4  __attribute__((ext_vector_type(4)));
typedef unsigned short ushort_t;
typedef unsigned long long u64;

__device__ __forceinline__ float ssp(float x) {
    return fmaxf(x, 0.0f) + __logf(1.0f + __expf(-fabsf(x))) - LOG2_;
}
__device__ __forceinline__ ushort_t f2bf(float x) {
    __hip_bfloat16 b = __float2bfloat16(x);
    return *reinterpret_cast<ushort_t*>(&b);
}
__device__ __forceinline__ float bf2f(ushort_t u) {
    return __uint_as_float(((unsigned)u) << 16);
}
__device__ __forceinline__ float4 f4zero() { return make_float4(0.f, 0.f, 0.f, 0.f); }

// ---------------------------------------------------------------------------
// Weight prep: node-side weights to bf16 hi/lo B-frag layout [n][k].
// ---------------------------------------------------------------------------
__global__ __launch_bounds__(256) void prep_weights(const float* __restrict__ Wlin,
                                                    const float* __restrict__ Wm1,
                                                    const float* __restrict__ Wm2,
                                                    ushort_t* __restrict__ wlhi,
                                                    ushort_t* __restrict__ wllo,
                                                    ushort_t* __restrict__ wm1hi,
                                                    ushort_t* __restrict__ wm1lo,
                                                    ushort_t* __restrict__ wm2hi,
                                                    ushort_t* __restrict__ wm2lo) {
    int idx = blockIdx.x * 256 + threadIdx.x;   // 0..16383
    int n = idx >> 7, k = idx & 127;
    {   float w = Wlin[(size_t)n * CH + k];     // y = x @ W^T  -> B[n][k] = W[n][k]
        ushort_t hi = f2bf(w); wlhi[n * CH + k] = hi; wllo[n * CH + k] = f2bf(w - bf2f(hi)); }
    {   float w = Wm1[(size_t)k * CH + n];      // y = x @ W    -> B[n][k] = W[k][n]
        ushort_t hi = f2bf(w); wm1hi[n * CH + k] = hi; wm1lo[n * CH + k] = f2bf(w - bf2f(hi)); }
    {   float w = Wm2[(size_t)k * CH + n];
        ushort_t hi = f2bf(w); wm2hi[n * CH + k] = hi; wm2lo[n * CH + k] = f2bf(w - bf2f(hi)); }
}

// ---------------------------------------------------------------------------
// ef(r) lookup table: exact fp32 pipeline at 4096 grid points over [0,5].
// ---------------------------------------------------------------------------
__global__ __launch_bounds__(128) void table_build(const float* __restrict__ Wf1,
                                                   const float* __restrict__ bf1,
                                                   const float* __restrict__ Wf2,
                                                   const float* __restrict__ bf2,
                                                   float* __restrict__ tab) {
    __shared__ float bas[64];
    __shared__ float t1[128];
    const int g = blockIdx.x, tid = threadIdx.x;
    const float r = (float)g * (5.0f / (float)(NR - 1));
    if (tid < 64) {
        float v = 0.f;
        if (tid < NF) { float d = r - (float)tid * DELTA; v = __expf(-COEF * d * d); }
        bas[tid] = v;
    }
    __syncthreads();
    float acc = bf1[tid];
    for (int k = 0; k < NF; k++) acc = fmaf(bas[k], Wf1[k * CH + tid], acc);
    t1[tid] = ssp(acc);
    __syncthreads();
    float acc2 = bf2[tid];
    for (int k = 0; k < CH; k++) acc2 = fmaf(t1[k], Wf2[k * CH + tid], acc2);
    tab[(size_t)g * CH + tid] = acc2;
}

// Pack lerp endpoints: tabi[g][c] = bf16(tab[g][c]) | bf16(tab[g+1][c])<<16.
__global__ __launch_bounds__(256) void table_pack(const float* __restrict__ tab,
                                                  unsigned* __restrict__ tabi) {
    int idx = blockIdx.x * 256 + threadIdx.x;   // 0 .. NR*CH-1
    int g = idx >> 7, c = idx & 127;
    float a = tab[(size_t)g * CH + c];
    float b = tab[(size_t)min(g + 1, NR - 1) * CH + c];
    tabi[(size_t)g * CH + c] = (unsigned)f2bf(a) | ((unsigned)f2bf(b) << 16);
}

// ---------------------------------------------------------------------------
// Two-pass bucket sort of edges by receiver.
// Record: send(16b) | recv(16b) | x_bits(32b).
// ---------------------------------------------------------------------------
__global__ __launch_bounds__(256) void bucket_hist(const int* __restrict__ recv,
                                                   int* __restrict__ bcnt) {
    __shared__ int bh[NB];
    const int tid = threadIdx.x;
    for (int i = tid; i < NB; i += 256) bh[i] = 0;
    __syncthreads();
    const int e0 = blockIdx.x * PASSA_CHUNK;
#pragma unroll
    for (int i = 0; i < 16; i++) {
        int e = e0 + tid + i * 256;
        if (e < N_EDGES) atomicAdd(&bh[recv[e] / BUCKET_NODES], 1);
    }
    __syncthreads();
    for (int i = tid; i < NB; i += 256)
        if (bh[i]) atomicAdd(&bcnt[i], bh[i]);
}

__global__ __launch_bounds__(256) void bucket_scan(const int* __restrict__ bcnt,
                                                   int* __restrict__ bbase,
                                                   int* __restrict__ bcursor) {
    __shared__ int s[NB];
    const int tid = threadIdx.x;
    s[tid] = bcnt[tid];
    s[tid + 256] = bcnt[tid + 256];
    __syncthreads();
    if (tid == 0) {
        int acc = 0;
        for (int i = 0; i < NB; i++) { int c = s[i]; s[i] = acc; acc += c; }
    }
    __syncthreads();
    bbase[tid] = s[tid];           bbase[tid + 256] = s[tid + 256];
    bcursor[tid] = s[tid];         bcursor[tid + 256] = s[tid + 256];
    if (tid == 0) bbase[NB] = N_EDGES;
}

__global__ __launch_bounds__(256) void bucket_scatter(const int* __restrict__ recv,
                                                      const int* __restrict__ send,
                                                      const float* __restrict__ dist,
                                                      int* __restrict__ bcursor,
                                                      u64* __restrict__ brec) {
    __shared__ int bbaseL[NB];
    __shared__ int bcur[NB];
    const int tid = threadIdx.x;
    for (int i = tid; i < NB; i += 256) bcur[i] = 0;
    __syncthreads();
    const int e0 = blockIdx.x * PASSA_CHUNK;
#pragma unroll
    for (int i = 0; i < 16; i++) {
        int e = e0 + tid + i * 256;
        if (e < N_EDGES) atomicAdd(&bcur[recv[e] / BUCKET_NODES], 1);
    }
    __syncthreads();
    for (int i = tid; i < NB; i += 256) {
        int c = bcur[i];
        if (c) bbaseL[i] = atomicAdd(&bcursor[i], c);
        bcur[i] = 0;
    }
    __syncthreads();
#pragma unroll
    for (int i = 0; i < 16; i++) {
        int e = e0 + tid + i * 256;
        if (e < N_EDGES) {
            int r = recv[e];
            int b = r / BUCKET_NODES;
            int rank = atomicAdd(&bcur[b], 1);
            float x = fminf(dist[e] * RSCALE, (float)(NR - 1));
            u64 rec = (u64)(unsigned)(send[e] | (r << 16)) |
                      ((u64)__float_as_uint(x) << 32);
            brec[bbaseL[b] + rank] = rec;
        }
    }
}

// One workgroup per bucket: node-sort its ~3.1K edges entirely in LDS.
__global__ __launch_bounds__(256) void bucket_sort(const int* __restrict__ bbase,
                                                   const u64* __restrict__ brec,
                                                   u64* __restrict__ meta,
                                                   int* __restrict__ cursor) {
    __shared__ int shist[BUCKET_NODES];
    __shared__ int sexc[BUCKET_NODES];
    __shared__ u64 sout[PASSB_CAP];
    const int b = blockIdx.x, tid = threadIdx.x;
    const int nbase = b * BUCKET_NODES;
    const int nn = min(BUCKET_NODES, N_NODES - nbase);
    if (nn <= 0) return;
    const int ebase = bbase[b], m = bbase[b + 1] - ebase;

    for (int i = tid; i < nn; i += 256) shist[i] = 0;
    __syncthreads();
    for (int i = tid; i < m; i += 256) {
        int l = (int)((brec[ebase + i] >> 16) & 0xFFFF) - nbase;
        atomicAdd(&shist[l], 1);
    }
    __syncthreads();
    if (tid == 0) {
        int acc = 0;
        for (int l = 0; l < nn; l++) { sexc[l] = acc; acc += shist[l]; }
    }
    __syncthreads();
    for (int l = tid; l < nn; l += 256)
        cursor[nbase + l] = ebase + sexc[l] + shist[l];
    __syncthreads();
    for (int i = tid; i < m; i += 256) {
        u64 rec = brec[ebase + i];
        int l = (int)((rec >> 16) & 0xFFFF) - nbase;
        int rank = atomicAdd(&sexc[l], 1);
        if (rank < PASSB_CAP) sout[rank] = rec;
    }
    __syncthreads();
    for (int i = tid; i < m; i += 256) meta[ebase + i] = sout[i];
}

// ---------------------------------------------------------------------------
// dense_h: h = features @ Wlin^T, output bf16.
// ---------------------------------------------------------------------------
__global__ __launch_bounds__(256) void dense_h(const float* __restrict__ X,
                                               const ushort_t* __restrict__ Bhi,
                                               const ushort_t* __restrict__ Blo,
                                               ushort_t* __restrict__ Y, int M) {
    __shared__ ushort_t xs[64][136];
    const int tid  = threadIdx.x;
    const int row0 = blockIdx.x * 64;

#pragma unroll
    for (int i = 0; i < 8; i++) {
        int idx = tid + i * 256;
        int r   = idx >> 5;
        int c4  = (idx & 31) * 4;
        float4 v = (row0 + r < M) ? *(const float4*)&X[(size_t)(row0 + r) * CH + c4]
                                  : f4zero();
        ushort4 s;
        s.x = f2bf(v.x); s.y = f2bf(v.y); s.z = f2bf(v.z); s.w = f2bf(v.w);
        *(ushort4*)&xs[r][c4] = s;
    }
    __syncthreads();

    const int lane = tid & 63;
    const int wv   = tid >> 6;
    const int row  = lane & 15;
    const int quad = lane >> 4;
    const int c0   = (2 * wv) * 16 + row;
    const int c1   = c0 + 16;

    f32x4 acc[2][4];
#pragma unroll
    for (int j = 0; j < 2; j++)
#pragma unroll
        for (int rt = 0; rt < 4; rt++) acc[j][rt] = (f32x4){0.f, 0.f, 0.f, 0.f};

#pragma unroll
    for (int kb = 0; kb < 128; kb += 32) {
        bf16x8 B0h = *(const bf16x8*)&Bhi[(size_t)c0 * CH + kb + quad * 8];
        bf16x8 B0l = *(const bf16x8*)&Blo[(size_t)c0 * CH + kb + quad * 8];
        bf16x8 B1h = *(const bf16x8*)&Bhi[(size_t)c1 * CH + kb + quad * 8];
        bf16x8 B1l = *(const bf16x8*)&Blo[(size_t)c1 * CH + kb + quad * 8];
#pragma unroll
        for (int rt = 0; rt < 4; rt++) {
            bf16x8 A = *(const bf16x8*)&xs[rt * 16 + row][kb + quad * 8];
            acc[0][rt] = __builtin_amdgcn_mfma_f32_16x16x32_bf16(A, B0l, acc[0][rt], 0, 0, 0);
            acc[0][rt] = __builtin_amdgcn_mfma_f32_16x16x32_bf16(A, B0h, acc[0][rt], 0, 0, 0);
            acc[1][rt] = __builtin_amdgcn_mfma_f32_16x16x32_bf16(A, B1l, acc[1][rt], 0, 0, 0);
            acc[1][rt] = __builtin_amdgcn_mfma_f32_16x16x32_bf16(A, B1h, acc[1][rt], 0, 0, 0);
        }
    }

#pragma unroll
    for (int j = 0; j < 2; j++) {
        int c = j ? c1 : c0;
#pragma unroll
        for (int rt = 0; rt < 4; rt++)
#pragma unroll
            for (int rg = 0; rg < 4; rg++) {
                int r = row0 + rt * 16 + quad * 4 + rg;
                if (r < M) Y[(size_t)r * CH + c] = f2bf(acc[j][rt][rg]);
            }
    }
}

// ---------------------------------------------------------------------------
// Fused output MLP: out = ssp(aggb @ Wm1 + bm1) @ Wm2 + bm2.
// aggb is already bf16 — staging is a straight copy, no cvt.
// ---------------------------------------------------------------------------
__global__ __launch_bounds__(256) void out_mlp(const ushort_t* __restrict__ AGG,
                                               const ushort_t* __restrict__ B1hi,
                                               const ushort_t* __restrict__ B1lo,
                                               const float* __restrict__ bm1,
                                               const ushort_t* __restrict__ B2hi,
                                               const ushort_t* __restrict__ B2lo,
                                               const float* __restrict__ bm2,
                                               float* __restrict__ OUT, int M) {
    __shared__ ushort_t xs[64][136];
    __shared__ ushort_t ts[64][136];
    const int tid  = threadIdx.x;
    const int row0 = blockIdx.x * 64;

#pragma unroll
    for (int i = 0; i < 4; i++) {
        int idx = tid + i * 256;            // 0..1023
        int r   = idx >> 4;                 // 0..63
        int c8  = (idx & 15) * 8;
        uint4 v = (row0 + r < M) ? *(const uint4*)&AGG[(size_t)(row0 + r) * CH + c8]
                                 : make_uint4(0, 0, 0, 0);
        *(uint4*)&xs[r][c8] = v;
    }
    __syncthreads();

    const int lane = tid & 63;
    const int wv   = tid >> 6;
    const int row  = lane & 15;
    const int quad = lane >> 4;
    const int c0   = (2 * wv) * 16 + row;
    const int c1   = c0 + 16;

    f32x4 acc[2][4];
#pragma unroll
    for (int j = 0; j < 2; j++)
#pragma unroll
        for (int rt = 0; rt < 4; rt++) acc[j][rt] = (f32x4){0.f, 0.f, 0.f, 0.f};

    // GEMM-A: t = ssp(agg @ Wm1 + bm1)
#pragma unroll
    for (int kb = 0; kb < 128; kb += 32) {
        bf16x8 B0h = *(const bf16x8*)&B1hi[(size_t)c0 * CH + kb + quad * 8];
        bf16x8 B0l = *(const bf16x8*)&B1lo[(size_t)c0 * CH + kb + quad * 8];
        bf16x8 B1h_ = *(const bf16x8*)&B1hi[(size_t)c1 * CH + kb + quad * 8];
        bf16x8 B1l_ = *(const bf16x8*)&B1lo[(size_t)c1 * CH + kb + quad * 8];
#pragma unroll
        for (int rt = 0; rt < 4; rt++) {
            bf16x8 A = *(const bf16x8*)&xs[rt * 16 + row][kb + quad * 8];
            acc[0][rt] = __builtin_amdgcn_mfma_f32_16x16x32_bf16(A, B0l, acc[0][rt], 0, 0, 0);
            acc[0][rt] = __builtin_amdgcn_mfma_f32_16x16x32_bf16(A, B0h, acc[0][rt], 0, 0, 0);
            acc[1][rt] = __builtin_amdgcn_mfma_f32_16x16x32_bf16(A, B1l_, acc[1][rt], 0, 0, 0);
            acc[1][rt] = __builtin_amdgcn_mfma_f32_16x16x32_bf16(A, B1h_, acc[1][rt], 0, 0, 0);
        }
    }
    {
        float bv[2] = { bm1[c0], bm1[c1] };
#pragma unroll
        for (int j = 0; j < 2; j++) {
            int c = j ? c1 : c0;
#pragma unroll
            for (int rt = 0; rt < 4; rt++)
#pragma unroll
                for (int rg = 0; rg < 4; rg++)
                    ts[rt * 16 + quad * 4 + rg][c] = f2bf(ssp(acc[j][rt][rg] + bv[j]));
        }
    }
    __syncthreads();

    // GEMM-B: out = t @ Wm2 + bm2
#pragma unroll
    for (int j = 0; j < 2; j++)
#pragma unroll
        for (int rt = 0; rt < 4; rt++) acc[j][rt] = (f32x4){0.f, 0.f, 0.f, 0.f};

#pragma unroll
    for (int kb = 0; kb < 128; kb += 32) {
        bf16x8 B0h = *(const bf16x8*)&B2hi[(size_t)c0 * CH + kb + quad * 8];
        bf16x8 B0l = *(const bf16x8*)&B2lo[(size_t)c0 * CH + kb + quad * 8];
        bf16x8 B1h_ = *(const bf16x8*)&B2hi[(size_t)c1 * CH + kb + quad * 8];
        bf16x8 B1l_ = *(const bf16x8*)&B2lo[(size_t)c1 * CH + kb + quad * 8];
#pragma unroll
        for (int rt = 0; rt < 4; rt++) {
            bf16x8 A = *(const bf16x8*)&ts[rt * 16 + row][kb + quad * 8];
            acc[0][rt] = __builtin_amdgcn_mfma_f32_16x16x32_bf16(A, B0l, acc[0][rt], 0, 0, 0);
            acc[0][rt] = __builtin_amdgcn_mfma_f32_16x16x32_bf16(A, B0h, acc[0][rt], 0, 0, 0);
            acc[1][rt] = __builtin_amdgcn_mfma_f32_16x16x32_bf16(A, B1l_, acc[1][rt], 0, 0, 0);
            acc[1][rt] = __builtin_amdgcn_mfma_f32_16x16x32_bf16(A, B1h_, acc[1][rt], 0, 0, 0);
        }
    }
    {
        float bv[2] = { bm2[c0], bm2[c1] };
#pragma unroll
        for (int j = 0; j < 2; j++) {
            int c = j ? c1 : c0;
#pragma unroll
            for (int rt = 0; rt < 4; rt++)
#pragma unroll
                for (int rg = 0; rg < 4; rg++) {
                    int r = row0 + rt * 16 + quad * 4 + rg;
                    if (r < M) OUT[(size_t)r * CH + c] = acc[j][rt][rg] + bv[j];
                }
        }
    }
}

// ---------------------------------------------------------------------------
// Edge gather: block owns 8 consecutive nodes. 32-thread group per node.
// Unrolled x4 with load-grouping for MLP (memory-level parallelism).
// ef lerp endpoints from packed bf16 table (one 16B load / 4 channels).
// agg written as bf16 (out_mlp rounds to bf16 anyway).
// ---------------------------------------------------------------------------
__global__ __launch_bounds__(256) void edge_gather(const int* __restrict__ cursor,
                                                   const u64* __restrict__ meta,
                                                   const ushort_t* __restrict__ h,
                                                   const unsigned* __restrict__ tabi,
                                                   ushort_t* __restrict__ aggb) {
    __shared__ u64 smeta[CHUNK];

    const int tid = threadIdx.x;
    const int n0  = blockIdx.x * NODES_PER_BLK;
    const int g   = tid >> 5;
    const int c4  = (tid & 31) * 4;
    const int n   = n0 + g;

    const int myend  = cursor[n];
    const int mybeg  = (n == 0) ? 0 : cursor[n - 1];
    const int blkbeg = (n0 == 0) ? 0 : cursor[n0 - 1];
    const int blkend = cursor[n0 + NODES_PER_BLK - 1];

    float4 macc = f4zero();

    for (int cs = blkbeg; cs < blkend; cs += CHUNK) {
        const int ce = min(cs + CHUNK, blkend);
        __syncthreads();
        for (int i = tid; i < ce - cs; i += 256) smeta[i] = meta[cs + i];
        __syncthreads();

        const int lo = max(mybeg, cs), hi = min(myend, ce);
        int e = lo;
        for (; e + 4 <= hi; e += 4) {
            int s[4]; float fr[4]; int ti[4];
#pragma unroll
            for (int u = 0; u < 4; u++) {
                u64 v = smeta[e - cs + u];
                s[u]  = (int)(v & 0xFFFF);
                float x  = __uint_as_float((unsigned)(v >> 32));
                float fx = floorf(x);
                ti[u] = min((int)fx, NR - 2);
                fr[u] = x - fx;
            }
            ushort4 hu[4]; uint4 tp[4];
#pragma unroll
            for (int u = 0; u < 4; u++) {
                hu[u] = *(const ushort4*)&h[(size_t)s[u] * CH + c4];
                tp[u] = *(const uint4*)&tabi[(size_t)ti[u] * CH + c4];
            }
#pragma unroll
            for (int u = 0; u < 4; u++) {
                float a, b, ef;
                a = __uint_as_float(tp[u].x << 16);
                b = __uint_as_float(tp[u].x & 0xFFFF0000u);
                ef = fmaf(fr[u], b - a, a);
                macc.x = fmaf(bf2f(hu[u].x), ef, macc.x);
                a = __uint_as_float(tp[u].y << 16);
                b = __uint_as_float(tp[u].y & 0xFFFF0000u);
                ef = fmaf(fr[u], b - a, a);
                macc.y = fmaf(bf2f(hu[u].y), ef, macc.y);
                a = __uint_as_float(tp[u].z << 16);
                b = __uint_as_float(tp[u].z & 0xFFFF0000u);
                ef = fmaf(fr[u], b - a, a);
                macc.z = fmaf(bf2f(hu[u].z), ef, macc.z);
                a = __uint_as_float(tp[u].w << 16);
                b = __uint_as_float(tp[u].w & 0xFFFF0000u);
                ef = fmaf(fr[u], b - a, a);
                macc.w = fmaf(bf2f(hu[u].w), ef, macc.w);
            }
        }
        for (; e < hi; e++) {
            u64 v = smeta[e - cs];
            int s = (int)(v & 0xFFFF);
            float x  = __uint_as_float((unsigned)(v >> 32));
            float fx = floorf(x);
            int ti = min((int)fx, NR - 2);
            float fr = x - fx;
            ushort4 hu = *(const ushort4*)&h[(size_t)s * CH + c4];
            uint4   tp = *(const uint4*)&tabi[(size_t)ti * CH + c4];
            float a, b, ef;
            a = __uint_as_float(tp.x << 16); b = __uint_as_float(tp.x & 0xFFFF0000u);
            ef = fmaf(fr, b - a, a); macc.x = fmaf(bf2f(hu.x), ef, macc.x);
            a = __uint_as_float(tp.y << 16); b = __uint_as_float(tp.y & 0xFFFF0000u);
            ef = fmaf(fr, b - a, a); macc.y = fmaf(bf2f(hu.y), ef, macc.y);
            a = __uint_as_float(tp.z << 16); b = __uint_as_float(tp.z & 0xFFFF0000u);
            ef = fmaf(fr, b - a, a); macc.z = fmaf(bf2f(hu.z), ef, macc.z);
            a = __uint_as_float(tp.w << 16); b = __uint_as_float(tp.w & 0xFFFF0000u);
            ef = fmaf(fr, b - a, a); macc.w = fmaf(bf2f(hu.w), ef, macc.w);
        }
    }

    ushort4 o;
    o.x = f2bf(macc.x); o.y = f2bf(macc.y); o.z = f2bf(macc.z); o.w = f2bf(macc.w);
    *(ushort4*)&aggb[(size_t)n * CH + c4] = o;
}

// ---------------------------------------------------------------------------
extern "C" void kernel_launch(void* const* d_in, const int* in_sizes, int n_in,
                              void* d_out, int out_size, void* d_ws, size_t ws_size,
                              hipStream_t stream) {
    const float* features = (const float*)d_in[0];
    const float* dist     = (const float*)d_in[1];
    const float* W_lin    = (const float*)d_in[2];
    const float* Wf1      = (const float*)d_in[3];
    const float* bf1      = (const float*)d_in[4];
    const float* Wf2      = (const float*)d_in[5];
    const float* bf2      = (const float*)d_in[6];
    const float* Wm1      = (const float*)d_in[7];
    const float* bm1      = (const float*)d_in[8];
    const float* Wm2      = (const float*)d_in[9];
    const float* bm2      = (const float*)d_in[10];
    const int* senders    = (const int*)d_in[11];
    const int* receivers  = (const int*)d_in[12];
    float* out = (float*)d_out;

    // workspace (~43 MB; harness provided >=51 MB in earlier rounds).
    // brec (12.8 MB) dead after bucket_sort -> reused as aggb (bf16 [N,128]).
    u64* brec       = (u64*)d_ws;                          // [E] 8B recs
    ushort_t* aggb  = (ushort_t*)d_ws;                     // alias of brec
    ushort_t* h     = (ushort_t*)(brec + N_EDGES);         // [N,128] bf16
    u64* meta       = (u64*)(h + (size_t)N_NODES * CH);    // [E] sorted recs
    float* tab      = (float*)(meta + N_EDGES);            // [NR,128] f32
    unsigned* tabi  = (unsigned*)(tab + (size_t)NR * CH);  // [NR,128] packed bf16 pair
    int* cursor     = (int*)(tabi + (size_t)NR * CH);      // [N]
    int* bcnt       = cursor + N_NODES;                    // [NB]
    int* bbase      = bcnt + NB;                           // [NB+1]
    int* bcursor    = bbase + NB + 1;                      // [NB]
    ushort_t* wlhi  = (ushort_t*)(bcursor + NB);
    ushort_t* wllo  = wlhi  + CH * CH;
    ushort_t* wm1hi = wllo  + CH * CH;
    ushort_t* wm1lo = wm1hi + CH * CH;
    ushort_t* wm2hi = wm1lo + CH * CH;
    ushort_t* wm2lo = wm2hi + CH * CH;

    hipMemsetAsync(bcnt, 0, NB * sizeof(int), stream);

    prep_weights<<<64, 256, 0, stream>>>(W_lin, Wm1, Wm2,
                                         wlhi, wllo, wm1hi, wm1lo, wm2hi, wm2lo);
    table_build<<<NR, 128, 0, stream>>>(Wf1, bf1, Wf2, bf2, tab);
    table_pack<<<(NR * CH) / 256, 256, 0, stream>>>(tab, tabi);

    const int nbA = (N_EDGES + PASSA_CHUNK - 1) / PASSA_CHUNK;   // 391
    bucket_hist<<<nbA, 256, 0, stream>>>(receivers, bcnt);
    bucket_scan<<<1, 256, 0, stream>>>(bcnt, bbase, bcursor);
    bucket_scatter<<<nbA, 256, 0, stream>>>(receivers, senders, dist, bcursor, brec);
    bucket_sort<<<NB, 256, 0, stream>>>(bbase, brec, meta, cursor);

    const int nb_dense = (N_NODES + 63) / 64;    // 782
    dense_h<<<nb_dense, 256, 0, stream>>>(features, wlhi, wllo, h, N_NODES);

    // gather/aggregate -> bf16 agg in workspace (no atomics)
    edge_gather<<<N_NODES / NODES_PER_BLK, 256, 0, stream>>>(cursor, meta, h, tabi, aggb);

    // fused output MLP -> d_out
    out_mlp<<<nb_dense, 256, 0, stream>>>(aggb, wm1hi, wm1lo, bm1, wm2hi, wm2lo, bm2, out, N_NODES);
}